// Round 1
// baseline (2432.743 us; speedup 1.0000x reference)
//
#include <hip/hip_runtime.h>
#include <climits>

#define VOXD 25
#define SLOT3 (VOXD*VOXD*VOXD)      // 15625
#define SLOTS (2*SLOT3)             // 31250
#define NCLS 8
#define TILE 512

struct Scalars {
  double hub;
  double cosSum;
  int n1;
  int nmd;
  int missCount;
  int nPure;
  int binA, rA, binB, rB;
  float thresh;
  int pad;
};

__device__ __forceinline__ int voxslot(int b, int vx, int vy, int vz) {
  return ((b * VOXD + vx) * VOXD + vy) * VOXD + vz;
}

__device__ __forceinline__ int incl_scan_1024(int v, int* sh) {
  int tid = threadIdx.x;
  sh[tid] = v;
  __syncthreads();
  for (int off = 1; off < 1024; off <<= 1) {
    int t = (tid >= off) ? sh[tid - off] : 0;
    __syncthreads();
    sh[tid] += t;
    __syncthreads();
  }
  return sh[tid];
}

// ---------------- K1: zero-init all read-before-write ws regions ----------------
__global__ void k_init(int* cnt, float* sx, float* sy, float* sz,
                       int* lmin, int* lmax, int* blCnt, float* blSum,
                       int* hists, Scalars* sc) {
  int i = blockIdx.x * blockDim.x + threadIdx.x;
  if (i < SLOTS) {
    cnt[i] = 0; sx[i] = 0.f; sy[i] = 0.f; sz[i] = 0.f;
    lmin[i] = INT_MAX; lmax[i] = INT_MIN;
  }
  if (i < 3 * 65536) hists[i] = 0;
  if (i < 16) { blCnt[i] = 0; blSum[3*i] = 0.f; blSum[3*i+1] = 0.f; blSum[3*i+2] = 0.f; }
  if (i == 0) {
    sc->hub = 0.0; sc->cosSum = 0.0; sc->n1 = 0; sc->nmd = 0;
    sc->missCount = 0; sc->nPure = 0;
  }
}

// ---------------- K2: per-point scatter into dense voxel table + (b,l) table ----
__global__ void k_scatter(const float* __restrict__ grid, const int* __restrict__ label,
                          const int* __restrict__ batch,
                          int* cnt, float* sx, float* sy, float* sz,
                          int* lmin, int* lmax, int* blCnt, float* blSum, int n) {
  int i = blockIdx.x * blockDim.x + threadIdx.x;
  if (i >= n) return;
  float gx = grid[3*i], gy = grid[3*i+1], gz = grid[3*i+2];
  int vx = (int)floorf(gx * (1.0f/16.0f));
  int vy = (int)floorf(gy * (1.0f/16.0f));
  int vz = (int)floorf(gz * (1.0f/16.0f));
  int b = batch[i], l = label[i];
  int s = voxslot(b, vx, vy, vz);
  atomicAdd(&cnt[s], 1);
  atomicAdd(&sx[s], gx); atomicAdd(&sy[s], gy); atomicAdd(&sz[s], gz);
  atomicMin(&lmin[s], l); atomicMax(&lmax[s], l);
  int bl = b * NCLS + l;
  atomicAdd(&blCnt[bl], 1);
  atomicAdd(&blSum[3*bl], gx); atomicAdd(&blSum[3*bl+1], gy); atomicAdd(&blSum[3*bl+2], gz);
}

// ---------------- K3: exclusive prefix over pure flags (slot order = rank order) -
__global__ void __launch_bounds__(1024) k_scan(const int* cnt, const int* lmin, const int* lmax,
                                               int* prefix, Scalars* sc) {
  __shared__ int sh[1024];
  int tid = threadIdx.x;
  int run = 0;
  for (int base = 0; base < SLOTS; base += 1024) {
    int i = base + tid;
    int f = 0;
    if (i < SLOTS) f = (cnt[i] > 0 && lmin[i] == lmax[i]) ? 1 : 0;
    int incl = incl_scan_1024(f, sh);
    if (i < SLOTS) prefix[i] = run + incl - f;
    run += sh[1023];
    __syncthreads();
  }
  if (tid == 0) sc->nPure = run;
}

// ---------------- K4: compact pure clusters (ascending slot = ascending rank) ----
__global__ void k_compact(const int* cnt, const float* sx, const float* sy, const float* sz,
                          const int* lmin, const int* lmax, const int* prefix,
                          int* pCode, float* pCx, float* pCy, float* pCz, float* pC2) {
  int s = blockIdx.x * blockDim.x + threadIdx.x;
  if (s >= SLOTS) return;
  int c = cnt[s];
  if (c <= 0 || lmin[s] != lmax[s]) return;
  int pos = prefix[s];
  float fc = (float)c;
  float cx = __fdiv_rn(sx[s], fc);
  float cy = __fdiv_rn(sy[s], fc);
  float cz = __fdiv_rn(sz[s], fc);
  int b = s / SLOT3;
  pCode[pos] = b * NCLS + lmin[s];
  pCx[pos] = cx; pCy[pos] = cy; pCz[pos] = cz;
  pC2[pos] = __fadd_rn(__fadd_rn(__fmul_rn(cx,cx), __fmul_rn(cy,cy)), __fmul_rn(cz,cz));
}

// ---------------- K5: per-point probe targets + miss list ------------------------
__global__ void k_targets(const float* __restrict__ grid, const int* __restrict__ label,
                          const int* __restrict__ batch,
                          const int* cnt, const float* sx, const float* sy, const float* sz,
                          const int* lmin, const int* lmax,
                          const int* blCnt, const float* blSum,
                          float* tgt, int* missIdx, Scalars* sc, int n) {
  int i = blockIdx.x * blockDim.x + threadIdx.x;
  if (i >= n) return;
  float gx = grid[3*i], gy = grid[3*i+1], gz = grid[3*i+2];
  int vx = (int)floorf(gx * (1.0f/16.0f));
  int vy = (int)floorf(gy * (1.0f/16.0f));
  int vz = (int)floorf(gz * (1.0f/16.0f));
  int b = batch[i], l = label[i];
  int s = voxslot(b, vx, vy, vz);

  float fc = (float)cnt[s];
  float ccx = __fdiv_rn(sx[s], fc);
  float ccy = __fdiv_rn(sy[s], fc);
  float ccz = __fdiv_rn(sz[s], fc);

  int bl = b * NCLS + l;
  float fbc = (float)max(blCnt[bl], 1);
  float gcx = __fdiv_rn(blSum[3*bl],   fbc);
  float gcy = __fdiv_rn(blSum[3*bl+1], fbc);
  float gcz = __fdiv_rn(blSum[3*bl+2], fbc);

  float dx = __fsub_rn(gcx, ccx);
  float dy = __fsub_rn(gcy, ccy);
  float dz = __fsub_rn(gcz, ccz);
  int sgx = (dx > 0.f) ? 1 : ((dx < 0.f) ? -1 : 0);
  int sgy = (dy > 0.f) ? 1 : ((dy < 0.f) ? -1 : 0);
  int sgz = (dz > 0.f) ? 1 : ((dz < 0.f) ? -1 : 0);

  bool purept = (lmin[s] == lmax[s]);

  float tx = gx, ty = gy, tz = gz;
  bool hit = false;
  for (int step = 1; step <= 2 && !hit; ++step) {
    int cvx = vx + sgx * step, cvy = vy + sgy * step, cvz = vz + sgz * step;
    if ((unsigned)cvx < (unsigned)VOXD && (unsigned)cvy < (unsigned)VOXD &&
        (unsigned)cvz < (unsigned)VOXD) {
      int s2 = voxslot(b, cvx, cvy, cvz);
      int c2 = cnt[s2];
      if (c2 > 0 && lmin[s2] == lmax[s2] && lmin[s2] == l) {
        float f2 = (float)c2;
        tx = __fdiv_rn(sx[s2], f2);
        ty = __fdiv_rn(sy[s2], f2);
        tz = __fdiv_rn(sz[s2], f2);
        hit = true;
      }
    }
  }
  tgt[3*i] = tx; tgt[3*i+1] = ty; tgt[3*i+2] = tz;
  if (!purept && !hit) {
    int p = atomicAdd(&sc->missCount, 1);
    missIdx[p] = i;
  }
}

// ---------------- K6: fallback nearest pure-cluster center (LDS-tiled) -----------
__global__ void k_fallback(const float* __restrict__ grid, const int* __restrict__ label,
                           const int* __restrict__ batch,
                           const int* pCode, const float* pCx, const float* pCy,
                           const float* pCz, const float* pC2,
                           const int* missIdx, const Scalars* sc, float* tgt) {
  __shared__ int   shCode[TILE];
  __shared__ float shX[TILE], shY[TILE], shZ[TILE], shS[TILE];
  int nMiss = sc->missCount;
  if ((int)(blockIdx.x * blockDim.x) >= nMiss) return;   // uniform per block
  int nPure = sc->nPure;
  int t = blockIdx.x * blockDim.x + threadIdx.x;

  int idx = -1, code = 0;
  float gx = 0.f, gy = 0.f, gz = 0.f, p2 = 0.f;
  if (t < nMiss) {
    idx = missIdx[t];
    gx = grid[3*idx]; gy = grid[3*idx+1]; gz = grid[3*idx+2];
    p2 = __fadd_rn(__fadd_rn(__fmul_rn(gx,gx), __fmul_rn(gy,gy)), __fmul_rn(gz,gz));
    code = batch[idx] * NCLS + label[idx];
  }
  float bestD = 1e38f;
  float bx = gx, by = gy, bz = gz;

  for (int base = 0; base < nPure; base += TILE) {
    int m = min(TILE, nPure - base);
    for (int j = threadIdx.x; j < m; j += blockDim.x) {
      shCode[j] = pCode[base+j];
      shX[j] = pCx[base+j]; shY[j] = pCy[base+j]; shZ[j] = pCz[base+j]; shS[j] = pC2[base+j];
    }
    __syncthreads();
    if (idx >= 0) {
      for (int j = 0; j < m; ++j) {
        if (shCode[j] != code) continue;
        float dot = __fadd_rn(__fadd_rn(__fmul_rn(gx,shX[j]), __fmul_rn(gy,shY[j])),
                              __fmul_rn(gz,shZ[j]));
        float d2 = __fadd_rn(__fsub_rn(p2, __fmul_rn(2.0f, dot)), shS[j]);
        if (d2 < bestD) { bestD = d2; bx = shX[j]; by = shY[j]; bz = shZ[j]; }
      }
    }
    __syncthreads();
  }
  if (idx >= 0 && bestD < 1e38f) {
    tgt[3*idx] = bx; tgt[3*idx+1] = by; tgt[3*idx+2] = bz;
  }
}

// ---------------- K7a: mag + high-16-bit histogram -------------------------------
__global__ void k_maghist(const float* __restrict__ grid, const float* __restrict__ tgt,
                          float* mag, int* histHi, int n) {
  int i = blockIdx.x * blockDim.x + threadIdx.x;
  if (i >= n) return;
  float tx = __fsub_rn(tgt[3*i],   grid[3*i]);
  float ty = __fsub_rn(tgt[3*i+1], grid[3*i+1]);
  float tz = __fsub_rn(tgt[3*i+2], grid[3*i+2]);
  float s = __fadd_rn(__fadd_rn(__fmul_rn(tx,tx), __fmul_rn(ty,ty)), __fmul_rn(tz,tz));
  float m = (s > 0.f) ? sqrtf(s) : 0.f;
  mag[i] = m;
  unsigned bits = __float_as_uint(m);
  atomicAdd(&histHi[bits >> 16], 1);
}

// ---------------- K7b: find high bins containing ranks r0, r1 --------------------
__global__ void __launch_bounds__(1024) k_selbins(const int* histHi, Scalars* sc,
                                                  int r0, int r1) {
  __shared__ int sh[1024];
  int tid = threadIdx.x;
  int run = 0;
  for (int base = 0; base < 65536; base += 1024) {
    int c = histHi[base + tid];
    int incl = incl_scan_1024(c, sh);
    int lo = run + incl - c, hi = run + incl;
    if (r0 >= lo && r0 < hi) { sc->binA = base + tid; sc->rA = r0 - lo; }
    if (r1 >= lo && r1 < hi) { sc->binB = base + tid; sc->rB = r1 - lo; }
    run += sh[1023];
    __syncthreads();
  }
}

// ---------------- K7c: low-16-bit histograms within selected bins ----------------
__global__ void k_hist2(const float* mag, const Scalars* sc, int* histA, int* histB, int n) {
  int i = blockIdx.x * blockDim.x + threadIdx.x;
  if (i >= n) return;
  unsigned bits = __float_as_uint(mag[i]);
  int h = (int)(bits >> 16);
  int lo = (int)(bits & 0xFFFFu);
  if (h == sc->binA) atomicAdd(&histA[lo], 1);
  if (h == sc->binB) atomicAdd(&histB[lo], 1);
}

// ---------------- K7d: resolve order statistics + lerp (numpy branch) ------------
__global__ void __launch_bounds__(1024) k_thresh(const int* histA, const int* histB,
                                                 Scalars* sc, double tfrac) {
  __shared__ int sh[1024];
  __shared__ int shLowA, shLowB;
  int tid = threadIdx.x;
  int rA = sc->rA, rB = sc->rB;
  int binA = sc->binA, binB = sc->binB;

  int run = 0;
  for (int base = 0; base < 65536; base += 1024) {
    int c = histA[base + tid];
    int incl = incl_scan_1024(c, sh);
    int lo = run + incl - c, hi = run + incl;
    if (rA >= lo && rA < hi) shLowA = base + tid;
    run += sh[1023];
    __syncthreads();
  }
  run = 0;
  for (int base = 0; base < 65536; base += 1024) {
    int c = histB[base + tid];
    int incl = incl_scan_1024(c, sh);
    int lo = run + incl - c, hi = run + incl;
    if (rB >= lo && rB < hi) shLowB = base + tid;
    run += sh[1023];
    __syncthreads();
  }
  if (tid == 0) {
    unsigned bitsLo = ((unsigned)binA << 16) | (unsigned)shLowA;
    unsigned bitsHi = ((unsigned)binB << 16) | (unsigned)shLowB;
    double a = (double)__uint_as_float(bitsLo);
    double b = (double)__uint_as_float(bitsHi);
    double t = tfrac;
    double th = (t >= 0.5) ? (b - (b - a) * (1.0 - t)) : (a + (b - a) * t);
    sc->thresh = (float)th;
  }
}

// ---------------- K8: masked huber + cosine reductions ---------------------------
__global__ void k_loss(const float* __restrict__ pred, const float* __restrict__ grid,
                       const float* __restrict__ tgt, const float* __restrict__ mag,
                       Scalars* sc, int n) {
  __shared__ double shH[256];
  __shared__ double shC[256];
  __shared__ int shN[256];
  __shared__ int shM[256];
  int tid = threadIdx.x;
  int i = blockIdx.x * blockDim.x + tid;
  double hub = 0.0, cs = 0.0;
  int c1 = 0, cmd = 0;
  if (i < n) {
    float th = sc->thresh;
    float m = mag[i];
    if (m <= th) {
      c1 = 1;
      float tox = __fsub_rn(tgt[3*i],   grid[3*i]);
      float toy = __fsub_rn(tgt[3*i+1], grid[3*i+1]);
      float toz = __fsub_rn(tgt[3*i+2], grid[3*i+2]);
      float px = pred[3*i], py = pred[3*i+1], pz = pred[3*i+2];
      float d0 = __fsub_rn(px, tox), d1 = __fsub_rn(py, toy), d2 = __fsub_rn(pz, toz);
      float a0 = fabsf(d0), a1 = fabsf(d1), a2 = fabsf(d2);
      float h0 = (a0 < 1.f) ? __fmul_rn(__fmul_rn(0.5f, d0), d0) : __fsub_rn(a0, 0.5f);
      float h1 = (a1 < 1.f) ? __fmul_rn(__fmul_rn(0.5f, d1), d1) : __fsub_rn(a1, 0.5f);
      float h2 = (a2 < 1.f) ? __fmul_rn(__fmul_rn(0.5f, d2), d2) : __fsub_rn(a2, 0.5f);
      hub = (double)h0 + (double)h1 + (double)h2;
      if (m > 0.f) {
        cmd = 1;
        float ps = __fadd_rn(__fadd_rn(__fmul_rn(px,px), __fmul_rn(py,py)), __fmul_rn(pz,pz));
        float pn = (ps > 0.f) ? sqrtf(ps) : 0.f;
        float dotp = __fadd_rn(__fadd_rn(__fmul_rn(px,tox), __fmul_rn(py,toy)),
                               __fmul_rn(pz,toz));
        float den = fmaxf(__fmul_rn(pn, m), 1e-4f);
        cs = (double)__fdiv_rn(dotp, den);
      }
    }
  }
  shH[tid] = hub; shC[tid] = cs; shN[tid] = c1; shM[tid] = cmd;
  __syncthreads();
  for (int off = 128; off > 0; off >>= 1) {
    if (tid < off) {
      shH[tid] += shH[tid+off];
      shC[tid] += shC[tid+off];
      shN[tid] += shN[tid+off];
      shM[tid] += shM[tid+off];
    }
    __syncthreads();
  }
  if (tid == 0) {
    atomicAdd(&sc->hub, shH[0]);
    atomicAdd(&sc->cosSum, shC[0]);
    atomicAdd(&sc->n1, shN[0]);
    atomicAdd(&sc->nmd, shM[0]);
  }
}

// ---------------- K9: finalize ---------------------------------------------------
__global__ void k_final(const Scalars* sc, float* out) {
  double n1 = (double)sc->n1;
  double l1 = (sc->n1 > 0) ? (sc->hub / fmax(n1 * 3.0, 1.0)) : 0.0;
  double nmd = (double)sc->nmd;
  double ld = (sc->nmd > 0) ? (1.0 - sc->cosSum / fmax(nmd, 1.0)) : 0.0;
  out[0] = (float)l1;
  out[1] = (float)ld;
}

extern "C" void kernel_launch(void* const* d_in, const int* in_sizes, int n_in,
                              void* d_out, int out_size, void* d_ws, size_t ws_size,
                              hipStream_t stream) {
  const float* pred  = (const float*)d_in[0];
  const float* grid  = (const float*)d_in[1];
  const int*   label = (const int*)d_in[2];
  const int*   batch = (const int*)d_in[3];
  int n = in_sizes[2];

  char* p = (char*)d_ws;
  auto take = [&](size_t bytes) -> char* {
    char* r = p;
    p += (bytes + 255) & ~(size_t)255;
    return r;
  };
  int*   cnt    = (int*)  take((size_t)SLOTS*4);
  float* sx     = (float*)take((size_t)SLOTS*4);
  float* sy     = (float*)take((size_t)SLOTS*4);
  float* sz     = (float*)take((size_t)SLOTS*4);
  int*   lmin   = (int*)  take((size_t)SLOTS*4);
  int*   lmax   = (int*)  take((size_t)SLOTS*4);
  int*   prefix = (int*)  take((size_t)(SLOTS+1)*4);
  int*   pCode  = (int*)  take((size_t)SLOTS*4);
  float* pCx    = (float*)take((size_t)SLOTS*4);
  float* pCy    = (float*)take((size_t)SLOTS*4);
  float* pCz    = (float*)take((size_t)SLOTS*4);
  float* pC2    = (float*)take((size_t)SLOTS*4);
  int*   blCnt  = (int*)  take(16*4);
  float* blSum  = (float*)take(48*4);
  int*   hists  = (int*)  take((size_t)3*65536*4);
  float* tgt    = (float*)take((size_t)n*3*4);
  float* mag    = (float*)take((size_t)n*4);
  int*   missIdx= (int*)  take((size_t)n*4);
  Scalars* sc   = (Scalars*)take(sizeof(Scalars));

  int* histHi = hists;
  int* histA  = hists + 65536;
  int* histB  = hists + 131072;

  int nb = (n + 255) / 256;

  k_init<<<768, 256, 0, stream>>>(cnt, sx, sy, sz, lmin, lmax, blCnt, blSum, hists, sc);
  k_scatter<<<nb, 256, 0, stream>>>(grid, label, batch, cnt, sx, sy, sz, lmin, lmax,
                                    blCnt, blSum, n);
  k_scan<<<1, 1024, 0, stream>>>(cnt, lmin, lmax, prefix, sc);
  k_compact<<<(SLOTS + 255) / 256, 256, 0, stream>>>(cnt, sx, sy, sz, lmin, lmax, prefix,
                                                     pCode, pCx, pCy, pCz, pC2);
  k_targets<<<nb, 256, 0, stream>>>(grid, label, batch, cnt, sx, sy, sz, lmin, lmax,
                                    blCnt, blSum, tgt, missIdx, sc, n);
  k_fallback<<<nb, 256, 0, stream>>>(grid, label, batch, pCode, pCx, pCy, pCz, pC2,
                                     missIdx, sc, tgt);
  k_maghist<<<nb, 256, 0, stream>>>(grid, tgt, mag, histHi, n);

  double vi = 0.99 * (double)(n - 1);
  int r0 = (int)vi;
  int r1 = r0 + 1; if (r1 > n - 1) r1 = n - 1;
  double tfrac = vi - (double)r0;

  k_selbins<<<1, 1024, 0, stream>>>(histHi, sc, r0, r1);
  k_hist2<<<nb, 256, 0, stream>>>(mag, sc, histA, histB, n);
  k_thresh<<<1, 1024, 0, stream>>>(histA, histB, sc, tfrac);
  k_loss<<<nb, 256, 0, stream>>>(pred, grid, tgt, mag, sc, n);
  k_final<<<1, 1, 0, stream>>>(sc, (float*)d_out);
}

// Round 2
// 653.249 us; speedup vs baseline: 3.7241x; 3.7241x over previous
//
#include <hip/hip_runtime.h>
#include <climits>

#define VOXD 25
#define SLOT3 (VOXD*VOXD*VOXD)      // 15625
#define SLOTS (2*SLOT3)             // 31250
#define NCLS 8
#define NCODE 16

struct Scalars {
  double hub;
  double cosSum;
  int n1;
  int nmd;
  int missCount;
  int nPure;
  int binA, rA, binB, rB;
  float thresh;
  int pad;
};

__device__ __forceinline__ int voxslot(int b, int vx, int vy, int vz) {
  return ((b * VOXD + vx) * VOXD + vy) * VOXD + vz;
}

// ---- fast block-wide inclusive scan (int), 1024 threads = 16 waves ----
__device__ __forceinline__ int block_scan_i(int v, int* ws, int* total) {
  int lane = threadIdx.x & 63, w = threadIdx.x >> 6;
  int s = v;
  #pragma unroll
  for (int off = 1; off < 64; off <<= 1) {
    int t = __shfl_up(s, off, 64);
    if (lane >= off) s += t;
  }
  if (lane == 63) ws[w] = s;
  __syncthreads();
  if (threadIdx.x < 16) {
    int x = ws[threadIdx.x];
    #pragma unroll
    for (int off = 1; off < 16; off <<= 1) {
      int t = __shfl_up(x, off, 64);
      if (lane >= off) x += t;
    }
    ws[threadIdx.x] = x;
  }
  __syncthreads();
  if (w > 0) s += ws[w - 1];
  *total = ws[15];
  __syncthreads();
  return s;
}

// ---- 4-lane packed u64 block scan (16 codes x 16-bit fields) ----
__device__ __forceinline__ void block_scan4_u64(unsigned long long v[4],
                                                unsigned long long* ws /*64*/,
                                                unsigned long long tot[4]) {
  int lane = threadIdx.x & 63, w = threadIdx.x >> 6;
  #pragma unroll
  for (int q = 0; q < 4; ++q) {
    unsigned long long s = v[q];
    #pragma unroll
    for (int off = 1; off < 64; off <<= 1) {
      unsigned long long t = __shfl_up(s, off, 64);
      if (lane >= off) s += t;
    }
    v[q] = s;
    if (lane == 63) ws[q * 16 + w] = s;
  }
  __syncthreads();
  if (threadIdx.x < 64) {
    int q = lane >> 4, idx = lane & 15;
    unsigned long long x = ws[q * 16 + idx];
    #pragma unroll
    for (int off = 1; off < 16; off <<= 1) {
      unsigned long long t = __shfl_up(x, off, 64);
      if (idx >= off) x += t;
    }
    ws[q * 16 + idx] = x;
  }
  __syncthreads();
  #pragma unroll
  for (int q = 0; q < 4; ++q) {
    if (w > 0) v[q] += ws[q * 16 + w - 1];
    tot[q] = ws[q * 16 + 15];
  }
  __syncthreads();
}

// ---------------- K1: zero-init all read-before-write ws regions ----------------
__global__ void k_init(int* cnt, float* sx, float* sy, float* sz,
                       int* lmin, int* lmax, int* blCnt, float* blSum,
                       int* hists, Scalars* sc) {
  int i = blockIdx.x * blockDim.x + threadIdx.x;
  if (i < SLOTS) {
    cnt[i] = 0; sx[i] = 0.f; sy[i] = 0.f; sz[i] = 0.f;
    lmin[i] = INT_MAX; lmax[i] = INT_MIN;
  }
  if (i < 3 * 65536) hists[i] = 0;
  if (i < 16) { blCnt[i] = 0; blSum[3*i] = 0.f; blSum[3*i+1] = 0.f; blSum[3*i+2] = 0.f; }
  if (i == 0) {
    sc->hub = 0.0; sc->cosSum = 0.0; sc->n1 = 0; sc->nmd = 0;
    sc->missCount = 0; sc->nPure = 0;
  }
}

// ---------------- K2: per-point scatter; LDS-aggregated (b,l) stats -------------
__global__ void k_scatter(const float* __restrict__ grid, const int* __restrict__ label,
                          const int* __restrict__ batch,
                          int* cnt, float* sx, float* sy, float* sz,
                          int* lmin, int* lmax, int* blCnt, float* blSum, int n) {
  __shared__ int sCnt[NCODE];
  __shared__ float sSum[3 * NCODE];
  int tid = threadIdx.x;
  if (tid < NCODE) sCnt[tid] = 0;
  if (tid < 3 * NCODE) sSum[tid] = 0.f;
  __syncthreads();
  int i = blockIdx.x * blockDim.x + tid;
  if (i < n) {
    float gx = grid[3*i], gy = grid[3*i+1], gz = grid[3*i+2];
    int vx = (int)floorf(gx * (1.0f/16.0f));
    int vy = (int)floorf(gy * (1.0f/16.0f));
    int vz = (int)floorf(gz * (1.0f/16.0f));
    int b = batch[i], l = label[i];
    int s = voxslot(b, vx, vy, vz);
    atomicAdd(&cnt[s], 1);
    atomicAdd(&sx[s], gx); atomicAdd(&sy[s], gy); atomicAdd(&sz[s], gz);
    atomicMin(&lmin[s], l); atomicMax(&lmax[s], l);
    int bl = b * NCLS + l;
    atomicAdd(&sCnt[bl], 1);
    atomicAdd(&sSum[3*bl], gx); atomicAdd(&sSum[3*bl+1], gy); atomicAdd(&sSum[3*bl+2], gz);
  }
  __syncthreads();
  if (tid < NCODE && sCnt[tid] != 0) atomicAdd(&blCnt[tid], sCnt[tid]);
  if (tid < 3 * NCODE && sSum[tid] != 0.f) atomicAdd(&blSum[tid], sSum[tid]);
}

// ---------------- K3: per-code (bucketed) prefix over pure flags -----------------
// Within-code order == slot order == cluster-rank order -> reference tie-breaks hold.
__global__ void __launch_bounds__(1024) k_scan(const int* cnt, const int* lmin, const int* lmax,
                                               int* prefix, int* codeBase, int* codeCnt,
                                               Scalars* sc) {
  __shared__ unsigned long long ws[64];
  unsigned long long run[4] = {0ULL, 0ULL, 0ULL, 0ULL};
  int tid = threadIdx.x;
  for (int base = 0; base < SLOTS; base += 1024) {
    int i = base + tid;
    int f = 0, c = 0;
    if (i < SLOTS && cnt[i] > 0 && lmin[i] == lmax[i]) {
      f = 1;
      c = (i / SLOT3) * NCLS + lmin[i];
    }
    unsigned long long v[4] = {0ULL, 0ULL, 0ULL, 0ULL};
    if (f) v[c >> 2] = 1ULL << (16 * (c & 3));
    unsigned long long tot[4];
    block_scan4_u64(v, ws, tot);
    if (f) {
      int q = c >> 2, sh16 = 16 * (c & 3);
      int incl = (int)(((run[q] + v[q]) >> sh16) & 0xFFFFULL);
      prefix[i] = incl - 1;   // within-code exclusive rank
    }
    #pragma unroll
    for (int q = 0; q < 4; ++q) run[q] += tot[q];
  }
  if (tid == 0) {
    int cum = 0;
    for (int c = 0; c < NCODE; ++c) {
      int cc = (int)((run[c >> 2] >> (16 * (c & 3))) & 0xFFFFULL);
      codeBase[c] = cum; codeCnt[c] = cc; cum += cc;
    }
    sc->nPure = cum;
  }
}

// ---------------- K4: compact pure clusters into per-code buckets (float4) -------
__global__ void k_compact(const int* cnt, const float* sx, const float* sy, const float* sz,
                          const int* lmin, const int* lmax, const int* prefix,
                          const int* codeBase, float4* pC) {
  int s = blockIdx.x * blockDim.x + threadIdx.x;
  if (s >= SLOTS) return;
  int c = cnt[s];
  if (c <= 0 || lmin[s] != lmax[s]) return;
  float fc = (float)c;
  float cx = __fdiv_rn(sx[s], fc);
  float cy = __fdiv_rn(sy[s], fc);
  float cz = __fdiv_rn(sz[s], fc);
  int code = (s / SLOT3) * NCLS + lmin[s];
  int pos = codeBase[code] + prefix[s];
  float c2 = __fadd_rn(__fadd_rn(__fmul_rn(cx,cx), __fmul_rn(cy,cy)), __fmul_rn(cz,cz));
  pC[pos] = make_float4(cx, cy, cz, c2);
}

// ---------------- K5: per-point probe targets + miss list ------------------------
__global__ void k_targets(const float* __restrict__ grid, const int* __restrict__ label,
                          const int* __restrict__ batch,
                          const int* cnt, const float* sx, const float* sy, const float* sz,
                          const int* lmin, const int* lmax,
                          const int* blCnt, const float* blSum,
                          float* tgt, int* missIdx, Scalars* sc, int n) {
  int i = blockIdx.x * blockDim.x + threadIdx.x;
  if (i >= n) return;
  float gx = grid[3*i], gy = grid[3*i+1], gz = grid[3*i+2];
  int vx = (int)floorf(gx * (1.0f/16.0f));
  int vy = (int)floorf(gy * (1.0f/16.0f));
  int vz = (int)floorf(gz * (1.0f/16.0f));
  int b = batch[i], l = label[i];
  int s = voxslot(b, vx, vy, vz);

  float fc = (float)cnt[s];
  float ccx = __fdiv_rn(sx[s], fc);
  float ccy = __fdiv_rn(sy[s], fc);
  float ccz = __fdiv_rn(sz[s], fc);

  int bl = b * NCLS + l;
  float fbc = (float)max(blCnt[bl], 1);
  float gcx = __fdiv_rn(blSum[3*bl],   fbc);
  float gcy = __fdiv_rn(blSum[3*bl+1], fbc);
  float gcz = __fdiv_rn(blSum[3*bl+2], fbc);

  float dx = __fsub_rn(gcx, ccx);
  float dy = __fsub_rn(gcy, ccy);
  float dz = __fsub_rn(gcz, ccz);
  int sgx = (dx > 0.f) ? 1 : ((dx < 0.f) ? -1 : 0);
  int sgy = (dy > 0.f) ? 1 : ((dy < 0.f) ? -1 : 0);
  int sgz = (dz > 0.f) ? 1 : ((dz < 0.f) ? -1 : 0);

  bool purept = (lmin[s] == lmax[s]);

  float tx = gx, ty = gy, tz = gz;
  bool hit = false;
  for (int step = 1; step <= 2 && !hit; ++step) {
    int cvx = vx + sgx * step, cvy = vy + sgy * step, cvz = vz + sgz * step;
    if ((unsigned)cvx < (unsigned)VOXD && (unsigned)cvy < (unsigned)VOXD &&
        (unsigned)cvz < (unsigned)VOXD) {
      int s2 = voxslot(b, cvx, cvy, cvz);
      int c2 = cnt[s2];
      if (c2 > 0 && lmin[s2] == lmax[s2] && lmin[s2] == l) {
        float f2 = (float)c2;
        tx = __fdiv_rn(sx[s2], f2);
        ty = __fdiv_rn(sy[s2], f2);
        tz = __fdiv_rn(sz[s2], f2);
        hit = true;
      }
    }
  }
  tgt[3*i] = tx; tgt[3*i+1] = ty; tgt[3*i+2] = tz;
  if (!purept && !hit) {
    int p = atomicAdd(&sc->missCount, 1);
    missIdx[p] = i;
  }
}

// ---------------- K6: fallback nearest pure center, per-code bucket scan ---------
__global__ void k_fallback(const float* __restrict__ grid, const int* __restrict__ label,
                           const int* __restrict__ batch,
                           const float4* __restrict__ pC,
                           const int* __restrict__ codeBase, const int* __restrict__ codeCnt,
                           const int* __restrict__ missIdx, const Scalars* sc, float* tgt) {
  int t = blockIdx.x * blockDim.x + threadIdx.x;
  if (t >= sc->missCount) return;
  int idx = missIdx[t];
  float gx = grid[3*idx], gy = grid[3*idx+1], gz = grid[3*idx+2];
  float p2 = __fadd_rn(__fadd_rn(__fmul_rn(gx,gx), __fmul_rn(gy,gy)), __fmul_rn(gz,gz));
  int code = batch[idx] * NCLS + label[idx];
  int j0 = codeBase[code];
  int j1 = j0 + codeCnt[code];

  float bestD = 1e38f;
  float bx = gx, by = gy, bz = gz;
  for (int j = j0; j < j1; ++j) {
    float4 c = pC[j];
    float dot = __fadd_rn(__fadd_rn(__fmul_rn(gx,c.x), __fmul_rn(gy,c.y)),
                          __fmul_rn(gz,c.z));
    float d2 = __fadd_rn(__fsub_rn(p2, __fmul_rn(2.0f, dot)), c.w);
    if (d2 < bestD) { bestD = d2; bx = c.x; by = c.y; bz = c.z; }
  }
  if (bestD < 1e38f) {
    tgt[3*idx] = bx; tgt[3*idx+1] = by; tgt[3*idx+2] = bz;
  }
}

// ---------------- K7a: mag + high-16-bit histogram -------------------------------
__global__ void k_maghist(const float* __restrict__ grid, const float* __restrict__ tgt,
                          float* mag, int* histHi, int n) {
  int i = blockIdx.x * blockDim.x + threadIdx.x;
  if (i >= n) return;
  float tx = __fsub_rn(tgt[3*i],   grid[3*i]);
  float ty = __fsub_rn(tgt[3*i+1], grid[3*i+1]);
  float tz = __fsub_rn(tgt[3*i+2], grid[3*i+2]);
  float s = __fadd_rn(__fadd_rn(__fmul_rn(tx,tx), __fmul_rn(ty,ty)), __fmul_rn(tz,tz));
  float m = (s > 0.f) ? sqrtf(s) : 0.f;
  mag[i] = m;
  unsigned bits = __float_as_uint(m);
  atomicAdd(&histHi[bits >> 16], 1);
}

// ---------------- K7b: find high bins containing ranks r0, r1 --------------------
__global__ void __launch_bounds__(1024) k_selbins(const int* histHi, Scalars* sc,
                                                  int r0, int r1) {
  __shared__ int ws[16];
  int tid = threadIdx.x;
  int run = 0;
  for (int base = 0; base < 65536; base += 1024) {
    int c = histHi[base + tid];
    int total;
    int incl = block_scan_i(c, ws, &total);
    int lo = run + incl - c, hi = run + incl;
    if (r0 >= lo && r0 < hi) { sc->binA = base + tid; sc->rA = r0 - lo; }
    if (r1 >= lo && r1 < hi) { sc->binB = base + tid; sc->rB = r1 - lo; }
    run += total;
  }
}

// ---------------- K7c: low-16-bit histograms within selected bins ----------------
__global__ void k_hist2(const float* mag, const Scalars* sc, int* histA, int* histB, int n) {
  int i = blockIdx.x * blockDim.x + threadIdx.x;
  if (i >= n) return;
  unsigned bits = __float_as_uint(mag[i]);
  int h = (int)(bits >> 16);
  int lo = (int)(bits & 0xFFFFu);
  if (h == sc->binA) atomicAdd(&histA[lo], 1);
  if (h == sc->binB) atomicAdd(&histB[lo], 1);
}

// ---------------- K7d: resolve order statistics + lerp (numpy branch) ------------
__global__ void __launch_bounds__(1024) k_thresh(const int* histA, const int* histB,
                                                 Scalars* sc, double tfrac) {
  __shared__ int ws[16];
  __shared__ int shLowA, shLowB;
  int tid = threadIdx.x;
  int rA = sc->rA, rB = sc->rB;
  int binA = sc->binA, binB = sc->binB;

  int run = 0;
  for (int base = 0; base < 65536; base += 1024) {
    int c = histA[base + tid];
    int total;
    int incl = block_scan_i(c, ws, &total);
    int lo = run + incl - c, hi = run + incl;
    if (rA >= lo && rA < hi) shLowA = base + tid;
    run += total;
  }
  run = 0;
  for (int base = 0; base < 65536; base += 1024) {
    int c = histB[base + tid];
    int total;
    int incl = block_scan_i(c, ws, &total);
    int lo = run + incl - c, hi = run + incl;
    if (rB >= lo && rB < hi) shLowB = base + tid;
    run += total;
  }
  __syncthreads();
  if (tid == 0) {
    unsigned bitsLo = ((unsigned)binA << 16) | (unsigned)shLowA;
    unsigned bitsHi = ((unsigned)binB << 16) | (unsigned)shLowB;
    double a = (double)__uint_as_float(bitsLo);
    double b = (double)__uint_as_float(bitsHi);
    double t = tfrac;
    double th = (t >= 0.5) ? (b - (b - a) * (1.0 - t)) : (a + (b - a) * t);
    sc->thresh = (float)th;
  }
}

// ---------------- K8: masked huber + cosine reductions ---------------------------
__global__ void k_loss(const float* __restrict__ pred, const float* __restrict__ grid,
                       const float* __restrict__ tgt, const float* __restrict__ mag,
                       Scalars* sc, int n) {
  __shared__ double shH[256];
  __shared__ double shC[256];
  __shared__ int shN[256];
  __shared__ int shM[256];
  int tid = threadIdx.x;
  int i = blockIdx.x * blockDim.x + tid;
  double hub = 0.0, cs = 0.0;
  int c1 = 0, cmd = 0;
  if (i < n) {
    float th = sc->thresh;
    float m = mag[i];
    if (m <= th) {
      c1 = 1;
      float tox = __fsub_rn(tgt[3*i],   grid[3*i]);
      float toy = __fsub_rn(tgt[3*i+1], grid[3*i+1]);
      float toz = __fsub_rn(tgt[3*i+2], grid[3*i+2]);
      float px = pred[3*i], py = pred[3*i+1], pz = pred[3*i+2];
      float d0 = __fsub_rn(px, tox), d1 = __fsub_rn(py, toy), d2 = __fsub_rn(pz, toz);
      float a0 = fabsf(d0), a1 = fabsf(d1), a2 = fabsf(d2);
      float h0 = (a0 < 1.f) ? __fmul_rn(__fmul_rn(0.5f, d0), d0) : __fsub_rn(a0, 0.5f);
      float h1 = (a1 < 1.f) ? __fmul_rn(__fmul_rn(0.5f, d1), d1) : __fsub_rn(a1, 0.5f);
      float h2 = (a2 < 1.f) ? __fmul_rn(__fmul_rn(0.5f, d2), d2) : __fsub_rn(a2, 0.5f);
      hub = (double)h0 + (double)h1 + (double)h2;
      if (m > 0.f) {
        cmd = 1;
        float ps = __fadd_rn(__fadd_rn(__fmul_rn(px,px), __fmul_rn(py,py)), __fmul_rn(pz,pz));
        float pn = (ps > 0.f) ? sqrtf(ps) : 0.f;
        float dotp = __fadd_rn(__fadd_rn(__fmul_rn(px,tox), __fmul_rn(py,toy)),
                               __fmul_rn(pz,toz));
        float den = fmaxf(__fmul_rn(pn, m), 1e-4f);
        cs = (double)__fdiv_rn(dotp, den);
      }
    }
  }
  shH[tid] = hub; shC[tid] = cs; shN[tid] = c1; shM[tid] = cmd;
  __syncthreads();
  for (int off = 128; off > 0; off >>= 1) {
    if (tid < off) {
      shH[tid] += shH[tid+off];
      shC[tid] += shC[tid+off];
      shN[tid] += shN[tid+off];
      shM[tid] += shM[tid+off];
    }
    __syncthreads();
  }
  if (tid == 0) {
    atomicAdd(&sc->hub, shH[0]);
    atomicAdd(&sc->cosSum, shC[0]);
    atomicAdd(&sc->n1, shN[0]);
    atomicAdd(&sc->nmd, shM[0]);
  }
}

// ---------------- K9: finalize ---------------------------------------------------
__global__ void k_final(const Scalars* sc, float* out) {
  double n1 = (double)sc->n1;
  double l1 = (sc->n1 > 0) ? (sc->hub / fmax(n1 * 3.0, 1.0)) : 0.0;
  double nmd = (double)sc->nmd;
  double ld = (sc->nmd > 0) ? (1.0 - sc->cosSum / fmax(nmd, 1.0)) : 0.0;
  out[0] = (float)l1;
  out[1] = (float)ld;
}

extern "C" void kernel_launch(void* const* d_in, const int* in_sizes, int n_in,
                              void* d_out, int out_size, void* d_ws, size_t ws_size,
                              hipStream_t stream) {
  const float* pred  = (const float*)d_in[0];
  const float* grid  = (const float*)d_in[1];
  const int*   label = (const int*)d_in[2];
  const int*   batch = (const int*)d_in[3];
  int n = in_sizes[2];

  char* p = (char*)d_ws;
  auto take = [&](size_t bytes) -> char* {
    char* r = p;
    p += (bytes + 255) & ~(size_t)255;
    return r;
  };
  int*    cnt     = (int*)   take((size_t)SLOTS*4);
  float*  sx      = (float*) take((size_t)SLOTS*4);
  float*  sy      = (float*) take((size_t)SLOTS*4);
  float*  sz      = (float*) take((size_t)SLOTS*4);
  int*    lmin    = (int*)   take((size_t)SLOTS*4);
  int*    lmax    = (int*)   take((size_t)SLOTS*4);
  int*    prefix  = (int*)   take((size_t)SLOTS*4);
  float4* pC      = (float4*)take((size_t)SLOTS*16);
  int*    codeBase= (int*)   take(NCODE*4);
  int*    codeCnt = (int*)   take(NCODE*4);
  int*    blCnt   = (int*)   take(16*4);
  float*  blSum   = (float*) take(48*4);
  int*    hists   = (int*)   take((size_t)3*65536*4);
  float*  tgt     = (float*) take((size_t)n*3*4);
  float*  mag     = (float*) take((size_t)n*4);
  int*    missIdx = (int*)   take((size_t)n*4);
  Scalars* sc     = (Scalars*)take(sizeof(Scalars));

  int* histHi = hists;
  int* histA  = hists + 65536;
  int* histB  = hists + 131072;

  int nb = (n + 255) / 256;

  k_init<<<768, 256, 0, stream>>>(cnt, sx, sy, sz, lmin, lmax, blCnt, blSum, hists, sc);
  k_scatter<<<nb, 256, 0, stream>>>(grid, label, batch, cnt, sx, sy, sz, lmin, lmax,
                                    blCnt, blSum, n);
  k_scan<<<1, 1024, 0, stream>>>(cnt, lmin, lmax, prefix, codeBase, codeCnt, sc);
  k_compact<<<(SLOTS + 255) / 256, 256, 0, stream>>>(cnt, sx, sy, sz, lmin, lmax, prefix,
                                                     codeBase, pC);
  k_targets<<<nb, 256, 0, stream>>>(grid, label, batch, cnt, sx, sy, sz, lmin, lmax,
                                    blCnt, blSum, tgt, missIdx, sc, n);
  k_fallback<<<nb, 256, 0, stream>>>(grid, label, batch, pC, codeBase, codeCnt,
                                     missIdx, sc, tgt);
  k_maghist<<<nb, 256, 0, stream>>>(grid, tgt, mag, histHi, n);

  double vi = 0.99 * (double)(n - 1);
  int r0 = (int)vi;
  int r1 = r0 + 1; if (r1 > n - 1) r1 = n - 1;
  double tfrac = vi - (double)r0;

  k_selbins<<<1, 1024, 0, stream>>>(histHi, sc, r0, r1);
  k_hist2<<<nb, 256, 0, stream>>>(mag, sc, histA, histB, n);
  k_thresh<<<1, 1024, 0, stream>>>(histA, histB, sc, tfrac);
  k_loss<<<nb, 256, 0, stream>>>(pred, grid, tgt, mag, sc, n);
  k_final<<<1, 1, 0, stream>>>(sc, (float*)d_out);
}

// Round 3
// 373.429 us; speedup vs baseline: 6.5146x; 1.7493x over previous
//
#include <hip/hip_runtime.h>
#include <climits>

#define VOXD 25
#define SLOT3 (VOXD*VOXD*VOXD)      // 15625
#define SLOTS (2*SLOT3)             // 31250
#define NCLS 8
#define NCODE 16
#define NBLK ((SLOTS + 255) / 256)  // 123

struct Scalars {
  double hub;
  double cosSum;
  int n1;
  int nmd;
  int missCount;
  int nPure;
  int binA, rA, binB, rB;
  float thresh;
  int pad;
};

__device__ __forceinline__ int voxslot(int b, int vx, int vy, int vz) {
  return ((b * VOXD + vx) * VOXD + vy) * VOXD + vz;
}

__device__ __forceinline__ int wave_incl_scan(int v) {
  int lane = threadIdx.x & 63;
  #pragma unroll
  for (int off = 1; off < 64; off <<= 1) {
    int t = __shfl_up(v, off, 64);
    if (lane >= off) v += t;
  }
  return v;
}

// ---- block-wide inclusive scan (int), 1024 threads = 16 waves ----
__device__ __forceinline__ int block_scan_i(int v, int* ws, int* total) {
  int lane = threadIdx.x & 63, w = threadIdx.x >> 6;
  int s = v;
  #pragma unroll
  for (int off = 1; off < 64; off <<= 1) {
    int t = __shfl_up(s, off, 64);
    if (lane >= off) s += t;
  }
  if (lane == 63) ws[w] = s;
  __syncthreads();
  if (threadIdx.x < 16) {
    int x = ws[threadIdx.x];
    #pragma unroll
    for (int off = 1; off < 16; off <<= 1) {
      int t = __shfl_up(x, off, 64);
      if (lane >= off) x += t;
    }
    ws[threadIdx.x] = x;
  }
  __syncthreads();
  if (w > 0) s += ws[w - 1];
  *total = ws[15];
  __syncthreads();
  return s;
}

// ---- 256-thread packed u64 scan (16 codes x 16-bit fields), 4 waves ----
__device__ __forceinline__ void scan4_256(unsigned long long v[4],
                                          unsigned long long* ws /*16*/) {
  int lane = threadIdx.x & 63, w = threadIdx.x >> 6;
  #pragma unroll
  for (int q = 0; q < 4; ++q) {
    unsigned long long s = v[q];
    #pragma unroll
    for (int off = 1; off < 64; off <<= 1) {
      unsigned long long t = __shfl_up(s, off, 64);
      if (lane >= off) s += t;
    }
    v[q] = s;
    if (lane == 63) ws[q * 4 + w] = s;
  }
  __syncthreads();
  if (threadIdx.x < 16) {
    int q = threadIdx.x >> 2, idx = threadIdx.x & 3;
    unsigned long long x = ws[q * 4 + idx];
    #pragma unroll
    for (int off = 1; off < 4; off <<= 1) {
      unsigned long long t = __shfl_up(x, off, 64);
      if (idx >= off) x += t;
    }
    ws[q * 4 + idx] = x;
  }
  __syncthreads();
  #pragma unroll
  for (int q = 0; q < 4; ++q) if (w > 0) v[q] += ws[q * 4 + w - 1];
}

// ---------------- K1: zero-init ----------------
__global__ void k_init(int* cnt, float* sx, float* sy, float* sz,
                       int* lmin, int* lmax, int* blCnt, float* blSum,
                       int* hists, Scalars* sc) {
  int i = blockIdx.x * blockDim.x + threadIdx.x;
  if (i < SLOTS) {
    cnt[i] = 0; sx[i] = 0.f; sy[i] = 0.f; sz[i] = 0.f;
    lmin[i] = INT_MAX; lmax[i] = INT_MIN;
  }
  if (i < 3 * 65536) hists[i] = 0;
  if (i < 16) { blCnt[i] = 0; blSum[3*i] = 0.f; blSum[3*i+1] = 0.f; blSum[3*i+2] = 0.f; }
  if (i == 0) {
    sc->hub = 0.0; sc->cosSum = 0.0; sc->n1 = 0; sc->nmd = 0;
    sc->missCount = 0; sc->nPure = 0;
  }
}

// ---------------- K2: per-point scatter; LDS-aggregated (b,l) stats -------------
__global__ void k_scatter(const float* __restrict__ grid, const int* __restrict__ label,
                          const int* __restrict__ batch,
                          int* cnt, float* sx, float* sy, float* sz,
                          int* lmin, int* lmax, int* blCnt, float* blSum, int n) {
  __shared__ int sCnt[NCODE];
  __shared__ float sSum[3 * NCODE];
  int tid = threadIdx.x;
  if (tid < NCODE) sCnt[tid] = 0;
  if (tid < 3 * NCODE) sSum[tid] = 0.f;
  __syncthreads();
  int i = blockIdx.x * blockDim.x + tid;
  if (i < n) {
    float gx = grid[3*i], gy = grid[3*i+1], gz = grid[3*i+2];
    int vx = (int)floorf(gx * (1.0f/16.0f));
    int vy = (int)floorf(gy * (1.0f/16.0f));
    int vz = (int)floorf(gz * (1.0f/16.0f));
    int b = batch[i], l = label[i];
    int s = voxslot(b, vx, vy, vz);
    atomicAdd(&cnt[s], 1);
    atomicAdd(&sx[s], gx); atomicAdd(&sy[s], gy); atomicAdd(&sz[s], gz);
    atomicMin(&lmin[s], l); atomicMax(&lmax[s], l);
    int bl = b * NCLS + l;
    atomicAdd(&sCnt[bl], 1);
    atomicAdd(&sSum[3*bl], gx); atomicAdd(&sSum[3*bl+1], gy); atomicAdd(&sSum[3*bl+2], gz);
  }
  __syncthreads();
  if (tid < NCODE && sCnt[tid] != 0) atomicAdd(&blCnt[tid], sCnt[tid]);
  if (tid < 3 * NCODE && sSum[tid] != 0.f) atomicAdd(&blSum[tid], sSum[tid]);
}

// ---------------- K3a: per-block per-code pure-cluster counts --------------------
__global__ void k_count(const int* cnt, const int* lmin, const int* lmax, int* blockCnt) {
  __shared__ int sc16[NCODE];
  if (threadIdx.x < NCODE) sc16[threadIdx.x] = 0;
  __syncthreads();
  int s = blockIdx.x * 256 + threadIdx.x;
  if (s < SLOTS && cnt[s] > 0 && lmin[s] == lmax[s])
    atomicAdd(&sc16[(s / SLOT3) * NCLS + lmin[s]], 1);
  __syncthreads();
  if (threadIdx.x < NCODE) blockCnt[blockIdx.x * NCODE + threadIdx.x] = sc16[threadIdx.x];
}

// ---------------- K3b: bases per (block,code) and per code -----------------------
__global__ void k_bases(const int* blockCnt, int* blockBase, int* codeBase,
                        int* codeCnt, Scalars* sc) {
  __shared__ int tot[NCODE];
  int c = threadIdx.x;
  if (c < NCODE) {
    int run = 0;
    for (int b = 0; b < NBLK; ++b) {
      blockBase[b * NCODE + c] = run;
      run += blockCnt[b * NCODE + c];
    }
    tot[c] = run;
  }
  __syncthreads();
  if (c == 0) {
    int cum = 0;
    for (int k = 0; k < NCODE; ++k) { codeBase[k] = cum; codeCnt[k] = tot[k]; cum += tot[k]; }
    sc->nPure = cum;
  }
}

// ---------------- K4: compact pure clusters into per-code buckets (float4) -------
// Within-code order == slot order == cluster-rank order -> reference tie-breaks hold.
__global__ void k_compact(const int* cnt, const float* sx, const float* sy, const float* sz,
                          const int* lmin, const int* lmax,
                          const int* blockBase, const int* codeBase, float4* pC) {
  __shared__ unsigned long long ws[16];
  int s = blockIdx.x * 256 + threadIdx.x;
  int f = 0, code = 0, c = 0;
  if (s < SLOTS) {
    c = cnt[s];
    if (c > 0 && lmin[s] == lmax[s]) { f = 1; code = (s / SLOT3) * NCLS + lmin[s]; }
  }
  unsigned long long v[4] = {0ULL, 0ULL, 0ULL, 0ULL};
  if (f) v[code >> 2] = 1ULL << (16 * (code & 3));
  scan4_256(v, ws);
  if (f) {
    int rank = (int)((v[code >> 2] >> (16 * (code & 3))) & 0xFFFFULL) - 1;
    int pos = codeBase[code] + blockBase[blockIdx.x * NCODE + code] + rank;
    float fc = (float)c;
    float cx = __fdiv_rn(sx[s], fc);
    float cy = __fdiv_rn(sy[s], fc);
    float cz = __fdiv_rn(sz[s], fc);
    float c2 = __fadd_rn(__fadd_rn(__fmul_rn(cx,cx), __fmul_rn(cy,cy)), __fmul_rn(cz,cz));
    pC[pos] = make_float4(cx, cy, cz, c2);
  }
}

// ---------------- K5: probe targets + miss list + mag/hist for non-miss ----------
__global__ void k_targets(const float* __restrict__ grid, const int* __restrict__ label,
                          const int* __restrict__ batch,
                          const int* cnt, const float* sx, const float* sy, const float* sz,
                          const int* lmin, const int* lmax,
                          const int* blCnt, const float* blSum,
                          float* tgt, float* mag, int* histHi,
                          int* missIdx, Scalars* sc, int n) {
  int i = blockIdx.x * blockDim.x + threadIdx.x;
  if (i >= n) return;
  float gx = grid[3*i], gy = grid[3*i+1], gz = grid[3*i+2];
  int vx = (int)floorf(gx * (1.0f/16.0f));
  int vy = (int)floorf(gy * (1.0f/16.0f));
  int vz = (int)floorf(gz * (1.0f/16.0f));
  int b = batch[i], l = label[i];
  int s = voxslot(b, vx, vy, vz);

  float fc = (float)cnt[s];
  float ccx = __fdiv_rn(sx[s], fc);
  float ccy = __fdiv_rn(sy[s], fc);
  float ccz = __fdiv_rn(sz[s], fc);

  int bl = b * NCLS + l;
  float fbc = (float)max(blCnt[bl], 1);
  float gcx = __fdiv_rn(blSum[3*bl],   fbc);
  float gcy = __fdiv_rn(blSum[3*bl+1], fbc);
  float gcz = __fdiv_rn(blSum[3*bl+2], fbc);

  float dx = __fsub_rn(gcx, ccx);
  float dy = __fsub_rn(gcy, ccy);
  float dz = __fsub_rn(gcz, ccz);
  int sgx = (dx > 0.f) ? 1 : ((dx < 0.f) ? -1 : 0);
  int sgy = (dy > 0.f) ? 1 : ((dy < 0.f) ? -1 : 0);
  int sgz = (dz > 0.f) ? 1 : ((dz < 0.f) ? -1 : 0);

  bool purept = (lmin[s] == lmax[s]);

  float tx = gx, ty = gy, tz = gz;
  bool hit = false;
  for (int step = 1; step <= 2 && !hit; ++step) {
    int cvx = vx + sgx * step, cvy = vy + sgy * step, cvz = vz + sgz * step;
    if ((unsigned)cvx < (unsigned)VOXD && (unsigned)cvy < (unsigned)VOXD &&
        (unsigned)cvz < (unsigned)VOXD) {
      int s2 = voxslot(b, cvx, cvy, cvz);
      int c2 = cnt[s2];
      if (c2 > 0 && lmin[s2] == lmax[s2] && lmin[s2] == l) {
        float f2 = (float)c2;
        tx = __fdiv_rn(sx[s2], f2);
        ty = __fdiv_rn(sy[s2], f2);
        tz = __fdiv_rn(sz[s2], f2);
        hit = true;
      }
    }
  }
  tgt[3*i] = tx; tgt[3*i+1] = ty; tgt[3*i+2] = tz;
  if (!purept && !hit) {
    int p = atomicAdd(&sc->missCount, 1);
    missIdx[p] = i;
  } else {
    float tox = __fsub_rn(tx, gx), toy = __fsub_rn(ty, gy), toz = __fsub_rn(tz, gz);
    float ssq = __fadd_rn(__fadd_rn(__fmul_rn(tox,tox), __fmul_rn(toy,toy)),
                          __fmul_rn(toz,toz));
    float m = (ssq > 0.f) ? sqrtf(ssq) : 0.f;
    mag[i] = m;
    atomicAdd(&histHi[__float_as_uint(m) >> 16], 1);
  }
}

// ---------------- K6: fallback — one wave per miss point, persistent grid --------
__global__ void k_fallback(const float* __restrict__ grid, const int* __restrict__ label,
                           const int* __restrict__ batch,
                           const float4* __restrict__ pC,
                           const int* __restrict__ codeBase, const int* __restrict__ codeCnt,
                           const int* __restrict__ missIdx, const Scalars* sc,
                           float* tgt, float* mag, int* histHi) {
  int lane = threadIdx.x & 63;
  int wid = (blockIdx.x * blockDim.x + threadIdx.x) >> 6;
  int nWaves = (gridDim.x * blockDim.x) >> 6;
  int nMiss = sc->missCount;

  for (int t = wid; t < nMiss; t += nWaves) {
    int idx = missIdx[t];
    float gx = grid[3*idx], gy = grid[3*idx+1], gz = grid[3*idx+2];
    float p2 = __fadd_rn(__fadd_rn(__fmul_rn(gx,gx), __fmul_rn(gy,gy)), __fmul_rn(gz,gz));
    int code = batch[idx] * NCLS + label[idx];
    int j0 = codeBase[code];
    int cc = codeCnt[code];

    float bestD = 1e38f;
    int bestJ = -1;
    for (int j = lane; j < cc; j += 64) {
      float4 c = pC[j0 + j];
      float dot = __fadd_rn(__fadd_rn(__fmul_rn(gx,c.x), __fmul_rn(gy,c.y)),
                            __fmul_rn(gz,c.z));
      float d2 = __fadd_rn(__fsub_rn(p2, __fmul_rn(2.0f, dot)), c.w);
      if (d2 < bestD) { bestD = d2; bestJ = j; }
    }
    // lexicographic (d2, j) min across the wave: monotone float key + index
    unsigned fb = __float_as_uint(bestD);
    fb = (fb >> 31) ? ~fb : (fb | 0x80000000u);
    unsigned long long key = ((unsigned long long)fb << 32) | (unsigned)bestJ;
    #pragma unroll
    for (int off = 1; off < 64; off <<= 1) {
      unsigned long long o = __shfl_xor(key, off, 64);
      key = (o < key) ? o : key;
    }
    if (lane == 0) {
      if (cc > 0) {
        int j = (int)(unsigned)(key & 0xFFFFFFFFULL);
        float4 c = pC[j0 + j];
        tgt[3*idx] = c.x; tgt[3*idx+1] = c.y; tgt[3*idx+2] = c.z;
        float tox = __fsub_rn(c.x, gx), toy = __fsub_rn(c.y, gy), toz = __fsub_rn(c.z, gz);
        float ssq = __fadd_rn(__fadd_rn(__fmul_rn(tox,tox), __fmul_rn(toy,toy)),
                              __fmul_rn(toz,toz));
        float m = (ssq > 0.f) ? sqrtf(ssq) : 0.f;
        mag[idx] = m;
        atomicAdd(&histHi[__float_as_uint(m) >> 16], 1);
      } else {
        mag[idx] = 0.f;
        atomicAdd(&histHi[0], 1);
      }
    }
  }
}

// ---------------- K7a: hierarchical select of high bins for ranks r0, r1 ---------
__global__ void __launch_bounds__(1024) k_selbins(const int* histHi, Scalars* sc,
                                                  int r0, int r1) {
  __shared__ int ws[16];
  __shared__ int chunk[2], off[2];
  int tid = threadIdx.x;
  int base = tid * 64;
  int s = 0;
  #pragma unroll 8
  for (int i = 0; i < 64; ++i) s += histHi[base + i];
  int total;
  int incl = block_scan_i(s, ws, &total);
  int lo = incl - s;
  if (r0 >= lo && r0 < incl) { chunk[0] = tid; off[0] = r0 - lo; }
  if (r1 >= lo && r1 < incl) { chunk[1] = tid; off[1] = r1 - lo; }
  __syncthreads();
  int w = tid >> 6, lane = tid & 63;
  if (w < 2) {
    int ch = chunk[w], ofs = off[w];
    int c = histHi[ch * 64 + lane];
    int inc = wave_incl_scan(c);
    if (ofs >= inc - c && ofs < inc) {
      if (w == 0) { sc->binA = ch * 64 + lane; sc->rA = ofs - (inc - c); }
      else        { sc->binB = ch * 64 + lane; sc->rB = ofs - (inc - c); }
    }
  }
}

// ---------------- K7b: low-16-bit histograms within selected bins ----------------
__global__ void k_hist2(const float* mag, const Scalars* sc, int* histA, int* histB, int n) {
  int i = blockIdx.x * blockDim.x + threadIdx.x;
  if (i >= n) return;
  unsigned bits = __float_as_uint(mag[i]);
  int h = (int)(bits >> 16);
  int lo = (int)(bits & 0xFFFFu);
  if (h == sc->binA) atomicAdd(&histA[lo], 1);
  if (h == sc->binB) atomicAdd(&histB[lo], 1);
}

// ---------------- K7c: resolve order statistics + lerp (numpy branch) ------------
__global__ void __launch_bounds__(1024) k_thresh(const int* histA, const int* histB,
                                                 Scalars* sc, double tfrac) {
  __shared__ int ws[16];
  __shared__ int chunkS, offS;
  __shared__ int lowA, lowB;
  int tid = threadIdx.x, lane = tid & 63;
  int rA = sc->rA, rB = sc->rB;
  int binA = sc->binA, binB = sc->binB;

  {
    int s = 0, base = tid * 64;
    #pragma unroll 8
    for (int i = 0; i < 64; ++i) s += histA[base + i];
    int total;
    int incl = block_scan_i(s, ws, &total);
    int lo = incl - s;
    if (rA >= lo && rA < incl) { chunkS = tid; offS = rA - lo; }
    __syncthreads();
    if (tid < 64) {
      int c = histA[chunkS * 64 + lane];
      int inc = wave_incl_scan(c);
      if (offS >= inc - c && offS < inc) lowA = chunkS * 64 + lane;
    }
    __syncthreads();
  }
  {
    int s = 0, base = tid * 64;
    #pragma unroll 8
    for (int i = 0; i < 64; ++i) s += histB[base + i];
    int total;
    int incl = block_scan_i(s, ws, &total);
    int lo = incl - s;
    if (rB >= lo && rB < incl) { chunkS = tid; offS = rB - lo; }
    __syncthreads();
    if (tid < 64) {
      int c = histB[chunkS * 64 + lane];
      int inc = wave_incl_scan(c);
      if (offS >= inc - c && offS < inc) lowB = chunkS * 64 + lane;
    }
    __syncthreads();
  }
  if (tid == 0) {
    unsigned bitsLo = ((unsigned)binA << 16) | (unsigned)lowA;
    unsigned bitsHi = ((unsigned)binB << 16) | (unsigned)lowB;
    double a = (double)__uint_as_float(bitsLo);
    double b = (double)__uint_as_float(bitsHi);
    double t = tfrac;
    double th = (t >= 0.5) ? (b - (b - a) * (1.0 - t)) : (a + (b - a) * t);
    sc->thresh = (float)th;
  }
}

// ---------------- K8: masked huber + cosine reductions ---------------------------
__global__ void k_loss(const float* __restrict__ pred, const float* __restrict__ grid,
                       const float* __restrict__ tgt, const float* __restrict__ mag,
                       Scalars* sc, int n) {
  __shared__ double shH[256];
  __shared__ double shC[256];
  __shared__ int shN[256];
  __shared__ int shM[256];
  int tid = threadIdx.x;
  int i = blockIdx.x * blockDim.x + tid;
  double hub = 0.0, cs = 0.0;
  int c1 = 0, cmd = 0;
  if (i < n) {
    float th = sc->thresh;
    float m = mag[i];
    if (m <= th) {
      c1 = 1;
      float tox = __fsub_rn(tgt[3*i],   grid[3*i]);
      float toy = __fsub_rn(tgt[3*i+1], grid[3*i+1]);
      float toz = __fsub_rn(tgt[3*i+2], grid[3*i+2]);
      float px = pred[3*i], py = pred[3*i+1], pz = pred[3*i+2];
      float d0 = __fsub_rn(px, tox), d1 = __fsub_rn(py, toy), d2 = __fsub_rn(pz, toz);
      float a0 = fabsf(d0), a1 = fabsf(d1), a2 = fabsf(d2);
      float h0 = (a0 < 1.f) ? __fmul_rn(__fmul_rn(0.5f, d0), d0) : __fsub_rn(a0, 0.5f);
      float h1 = (a1 < 1.f) ? __fmul_rn(__fmul_rn(0.5f, d1), d1) : __fsub_rn(a1, 0.5f);
      float h2 = (a2 < 1.f) ? __fmul_rn(__fmul_rn(0.5f, d2), d2) : __fsub_rn(a2, 0.5f);
      hub = (double)h0 + (double)h1 + (double)h2;
      if (m > 0.f) {
        cmd = 1;
        float ps = __fadd_rn(__fadd_rn(__fmul_rn(px,px), __fmul_rn(py,py)), __fmul_rn(pz,pz));
        float pn = (ps > 0.f) ? sqrtf(ps) : 0.f;
        float dotp = __fadd_rn(__fadd_rn(__fmul_rn(px,tox), __fmul_rn(py,toy)),
                               __fmul_rn(pz,toz));
        float den = fmaxf(__fmul_rn(pn, m), 1e-4f);
        cs = (double)__fdiv_rn(dotp, den);
      }
    }
  }
  shH[tid] = hub; shC[tid] = cs; shN[tid] = c1; shM[tid] = cmd;
  __syncthreads();
  for (int off = 128; off > 0; off >>= 1) {
    if (tid < off) {
      shH[tid] += shH[tid+off];
      shC[tid] += shC[tid+off];
      shN[tid] += shN[tid+off];
      shM[tid] += shM[tid+off];
    }
    __syncthreads();
  }
  if (tid == 0) {
    atomicAdd(&sc->hub, shH[0]);
    atomicAdd(&sc->cosSum, shC[0]);
    atomicAdd(&sc->n1, shN[0]);
    atomicAdd(&sc->nmd, shM[0]);
  }
}

// ---------------- K9: finalize ---------------------------------------------------
__global__ void k_final(const Scalars* sc, float* out) {
  double n1 = (double)sc->n1;
  double l1 = (sc->n1 > 0) ? (sc->hub / fmax(n1 * 3.0, 1.0)) : 0.0;
  double nmd = (double)sc->nmd;
  double ld = (sc->nmd > 0) ? (1.0 - sc->cosSum / fmax(nmd, 1.0)) : 0.0;
  out[0] = (float)l1;
  out[1] = (float)ld;
}

extern "C" void kernel_launch(void* const* d_in, const int* in_sizes, int n_in,
                              void* d_out, int out_size, void* d_ws, size_t ws_size,
                              hipStream_t stream) {
  const float* pred  = (const float*)d_in[0];
  const float* grid  = (const float*)d_in[1];
  const int*   label = (const int*)d_in[2];
  const int*   batch = (const int*)d_in[3];
  int n = in_sizes[2];

  char* p = (char*)d_ws;
  auto take = [&](size_t bytes) -> char* {
    char* r = p;
    p += (bytes + 255) & ~(size_t)255;
    return r;
  };
  int*    cnt      = (int*)   take((size_t)SLOTS*4);
  float*  sx       = (float*) take((size_t)SLOTS*4);
  float*  sy       = (float*) take((size_t)SLOTS*4);
  float*  sz       = (float*) take((size_t)SLOTS*4);
  int*    lmin     = (int*)   take((size_t)SLOTS*4);
  int*    lmax     = (int*)   take((size_t)SLOTS*4);
  float4* pC       = (float4*)take((size_t)SLOTS*16);
  int*    blockCnt = (int*)   take((size_t)NBLK*NCODE*4);
  int*    blockBase= (int*)   take((size_t)NBLK*NCODE*4);
  int*    codeBase = (int*)   take(NCODE*4);
  int*    codeCnt  = (int*)   take(NCODE*4);
  int*    blCnt    = (int*)   take(16*4);
  float*  blSum    = (float*) take(48*4);
  int*    hists    = (int*)   take((size_t)3*65536*4);
  float*  tgt      = (float*) take((size_t)n*3*4);
  float*  mag      = (float*) take((size_t)n*4);
  int*    missIdx  = (int*)   take((size_t)n*4);
  Scalars* sc      = (Scalars*)take(sizeof(Scalars));

  int* histHi = hists;
  int* histA  = hists + 65536;
  int* histB  = hists + 131072;

  int nb = (n + 255) / 256;

  k_init<<<768, 256, 0, stream>>>(cnt, sx, sy, sz, lmin, lmax, blCnt, blSum, hists, sc);
  k_scatter<<<nb, 256, 0, stream>>>(grid, label, batch, cnt, sx, sy, sz, lmin, lmax,
                                    blCnt, blSum, n);
  k_count<<<NBLK, 256, 0, stream>>>(cnt, lmin, lmax, blockCnt);
  k_bases<<<1, 64, 0, stream>>>(blockCnt, blockBase, codeBase, codeCnt, sc);
  k_compact<<<NBLK, 256, 0, stream>>>(cnt, sx, sy, sz, lmin, lmax, blockBase, codeBase, pC);
  k_targets<<<nb, 256, 0, stream>>>(grid, label, batch, cnt, sx, sy, sz, lmin, lmax,
                                    blCnt, blSum, tgt, mag, histHi, missIdx, sc, n);
  k_fallback<<<1024, 256, 0, stream>>>(grid, label, batch, pC, codeBase, codeCnt,
                                       missIdx, sc, tgt, mag, histHi);

  double vi = 0.99 * (double)(n - 1);
  int r0 = (int)vi;
  int r1 = r0 + 1; if (r1 > n - 1) r1 = n - 1;
  double tfrac = vi - (double)r0;

  k_selbins<<<1, 1024, 0, stream>>>(histHi, sc, r0, r1);
  k_hist2<<<nb, 256, 0, stream>>>(mag, sc, histA, histB, n);
  k_thresh<<<1, 1024, 0, stream>>>(histA, histB, sc, tfrac);
  k_loss<<<nb, 256, 0, stream>>>(pred, grid, tgt, mag, sc, n);
  k_final<<<1, 1, 0, stream>>>(sc, (float*)d_out);
}

// Round 4
// 373.283 us; speedup vs baseline: 6.5172x; 1.0004x over previous
//
#include <hip/hip_runtime.h>
#include <climits>

#define VOXD 25
#define SLOT3 (VOXD*VOXD*VOXD)      // 15625
#define SLOTS (2*SLOT3)             // 31250
#define NCLS 8
#define NCODE 16
#define NBLK ((SLOTS + 255) / 256)  // 123

struct Scalars {
  double hub;
  double cosSum;
  int n1;
  int nmd;
  int missCount;
  int nPure;
  int binA, rA, binB, rB;
  float thresh;
  int pad;
};

__device__ __forceinline__ int voxslot(int b, int vx, int vy, int vz) {
  return ((b * VOXD + vx) * VOXD + vy) * VOXD + vz;
}

__device__ __forceinline__ int wave_incl_scan(int v) {
  int lane = threadIdx.x & 63;
  #pragma unroll
  for (int off = 1; off < 64; off <<= 1) {
    int t = __shfl_up(v, off, 64);
    if (lane >= off) v += t;
  }
  return v;
}

// ---- block-wide inclusive scan (int), 1024 threads = 16 waves ----
__device__ __forceinline__ int block_scan_i(int v, int* ws, int* total) {
  int lane = threadIdx.x & 63, w = threadIdx.x >> 6;
  int s = v;
  #pragma unroll
  for (int off = 1; off < 64; off <<= 1) {
    int t = __shfl_up(s, off, 64);
    if (lane >= off) s += t;
  }
  if (lane == 63) ws[w] = s;
  __syncthreads();
  if (threadIdx.x < 16) {
    int x = ws[threadIdx.x];
    #pragma unroll
    for (int off = 1; off < 16; off <<= 1) {
      int t = __shfl_up(x, off, 64);
      if (lane >= off) x += t;
    }
    ws[threadIdx.x] = x;
  }
  __syncthreads();
  if (w > 0) s += ws[w - 1];
  *total = ws[15];
  __syncthreads();
  return s;
}

// ---- 256-thread packed u64 scan (16 codes x 16-bit fields), 4 waves ----
__device__ __forceinline__ void scan4_256(unsigned long long v[4],
                                          unsigned long long* ws /*16*/) {
  int lane = threadIdx.x & 63, w = threadIdx.x >> 6;
  #pragma unroll
  for (int q = 0; q < 4; ++q) {
    unsigned long long s = v[q];
    #pragma unroll
    for (int off = 1; off < 64; off <<= 1) {
      unsigned long long t = __shfl_up(s, off, 64);
      if (lane >= off) s += t;
    }
    v[q] = s;
    if (lane == 63) ws[q * 4 + w] = s;
  }
  __syncthreads();
  if (threadIdx.x < 16) {
    int q = threadIdx.x >> 2, idx = threadIdx.x & 3;
    unsigned long long x = ws[q * 4 + idx];
    #pragma unroll
    for (int off = 1; off < 4; off <<= 1) {
      unsigned long long t = __shfl_up(x, off, 64);
      if (idx >= off) x += t;
    }
    ws[q * 4 + idx] = x;
  }
  __syncthreads();
  #pragma unroll
  for (int q = 0; q < 4; ++q) if (w > 0) v[q] += ws[q * 4 + w - 1];
}

// ---------------- K1: zero-init ----------------
__global__ void k_init(int* cnt, float* sx, float* sy, float* sz, int* lmask,
                       int* blCnt, float* blSum, int* hists, Scalars* sc) {
  int i = blockIdx.x * blockDim.x + threadIdx.x;
  if (i < SLOTS) {
    cnt[i] = 0; sx[i] = 0.f; sy[i] = 0.f; sz[i] = 0.f; lmask[i] = 0;
  }
  if (i < 3 * 65536) hists[i] = 0;
  if (i < 16) { blCnt[i] = 0; blSum[3*i] = 0.f; blSum[3*i+1] = 0.f; blSum[3*i+2] = 0.f; }
  if (i == 0) {
    sc->hub = 0.0; sc->cosSum = 0.0; sc->n1 = 0; sc->nmd = 0;
    sc->missCount = 0; sc->nPure = 0;
  }
}

// ---------------- K2: per-point scatter; label bitmask; LDS-agg (b,l) stats ------
__global__ void k_scatter(const float* __restrict__ grid, const int* __restrict__ label,
                          const int* __restrict__ batch,
                          int* cnt, float* sx, float* sy, float* sz, int* lmask,
                          int* blCnt, float* blSum, int n) {
  __shared__ int sCnt[NCODE];
  __shared__ float sSum[3 * NCODE];
  int tid = threadIdx.x;
  if (tid < NCODE) sCnt[tid] = 0;
  if (tid < 3 * NCODE) sSum[tid] = 0.f;
  __syncthreads();
  int i = blockIdx.x * blockDim.x + tid;
  if (i < n) {
    float gx = grid[3*i], gy = grid[3*i+1], gz = grid[3*i+2];
    int vx = (int)floorf(gx * (1.0f/16.0f));
    int vy = (int)floorf(gy * (1.0f/16.0f));
    int vz = (int)floorf(gz * (1.0f/16.0f));
    int b = batch[i], l = label[i];
    int s = voxslot(b, vx, vy, vz);
    atomicAdd(&cnt[s], 1);
    atomicAdd(&sx[s], gx); atomicAdd(&sy[s], gy); atomicAdd(&sz[s], gz);
    atomicOr(&lmask[s], 1 << l);
    int bl = b * NCLS + l;
    atomicAdd(&sCnt[bl], 1);
    atomicAdd(&sSum[3*bl], gx); atomicAdd(&sSum[3*bl+1], gy); atomicAdd(&sSum[3*bl+2], gz);
  }
  __syncthreads();
  if (tid < NCODE && sCnt[tid] != 0) atomicAdd(&blCnt[tid], sCnt[tid]);
  if (tid < 3 * NCODE && sSum[tid] != 0.f) atomicAdd(&blSum[tid], sSum[tid]);
}

// ---------------- K3a: consolidate slot table to float4 + per-block code counts --
// ctr[s] = {cx, cy, cz, meta}; meta = label if pure, -1 if mixed, -2 if empty.
__global__ void k_prep(const int* cnt, const float* sx, const float* sy, const float* sz,
                       const int* lmask, float4* ctr, int* blockCnt) {
  __shared__ int sc16[NCODE];
  if (threadIdx.x < NCODE) sc16[threadIdx.x] = 0;
  __syncthreads();
  int s = blockIdx.x * 256 + threadIdx.x;
  if (s < SLOTS) {
    int c = cnt[s];
    float4 v = make_float4(0.f, 0.f, 0.f, __int_as_float(-2));
    if (c > 0) {
      float fc = (float)c;
      float cx = __fdiv_rn(sx[s], fc);
      float cy = __fdiv_rn(sy[s], fc);
      float cz = __fdiv_rn(sz[s], fc);
      int m = lmask[s];
      bool pure = (m & (m - 1)) == 0;      // c>0 -> m!=0
      int lbl = __ffs(m) - 1;
      int meta = pure ? lbl : -1;
      v = make_float4(cx, cy, cz, __int_as_float(meta));
      if (pure) atomicAdd(&sc16[(s / SLOT3) * NCLS + lbl], 1);
    }
    ctr[s] = v;
  }
  __syncthreads();
  if (threadIdx.x < NCODE) blockCnt[blockIdx.x * NCODE + threadIdx.x] = sc16[threadIdx.x];
}

// ---------------- K3b: bases per (block,code) and per code -----------------------
__global__ void k_bases(const int* blockCnt, int* blockBase, int* codeBase,
                        int* codeCnt, Scalars* sc) {
  __shared__ int tot[NCODE];
  int c = threadIdx.x;
  if (c < NCODE) {
    int run = 0;
    for (int b = 0; b < NBLK; ++b) {
      blockBase[b * NCODE + c] = run;
      run += blockCnt[b * NCODE + c];
    }
    tot[c] = run;
  }
  __syncthreads();
  if (c == 0) {
    int cum = 0;
    for (int k = 0; k < NCODE; ++k) { codeBase[k] = cum; codeCnt[k] = tot[k]; cum += tot[k]; }
    sc->nPure = cum;
  }
}

// ---------------- K4: compact pure clusters into per-code buckets (float4) -------
// Within-code order == slot order == cluster-rank order -> reference tie-breaks hold.
__global__ void k_compact(const float4* __restrict__ ctr,
                          const int* blockBase, const int* codeBase, float4* pC) {
  __shared__ unsigned long long ws[16];
  int s = blockIdx.x * 256 + threadIdx.x;
  int f = 0, code = 0;
  float4 cv = make_float4(0.f, 0.f, 0.f, 0.f);
  if (s < SLOTS) {
    cv = ctr[s];
    int meta = __float_as_int(cv.w);
    if (meta >= 0) { f = 1; code = (s / SLOT3) * NCLS + meta; }
  }
  unsigned long long v[4] = {0ULL, 0ULL, 0ULL, 0ULL};
  if (f) v[code >> 2] = 1ULL << (16 * (code & 3));
  scan4_256(v, ws);
  if (f) {
    int rank = (int)((v[code >> 2] >> (16 * (code & 3))) & 0xFFFFULL) - 1;
    int pos = codeBase[code] + blockBase[blockIdx.x * NCODE + code] + rank;
    float c2 = __fadd_rn(__fadd_rn(__fmul_rn(cv.x,cv.x), __fmul_rn(cv.y,cv.y)),
                         __fmul_rn(cv.z,cv.z));
    pC[pos] = make_float4(cv.x, cv.y, cv.z, c2);
  }
}

// ---------------- K5: probe targets (3 float4 gathers) + miss list + mag/hist ----
__global__ void k_targets(const float* __restrict__ grid, const int* __restrict__ label,
                          const int* __restrict__ batch,
                          const float4* __restrict__ ctr,
                          const int* __restrict__ blCnt, const float* __restrict__ blSum,
                          float* tgt, float* mag, int* histHi,
                          int* missIdx, Scalars* sc, int n) {
  int i = blockIdx.x * blockDim.x + threadIdx.x;
  if (i >= n) return;
  float gx = grid[3*i], gy = grid[3*i+1], gz = grid[3*i+2];
  int vx = (int)floorf(gx * (1.0f/16.0f));
  int vy = (int)floorf(gy * (1.0f/16.0f));
  int vz = (int)floorf(gz * (1.0f/16.0f));
  int b = batch[i], l = label[i];
  int s = voxslot(b, vx, vy, vz);

  float4 own = ctr[s];
  bool purept = (__float_as_int(own.w) >= 0);

  int bl = b * NCLS + l;
  float fbc = (float)max(blCnt[bl], 1);
  float gcx = __fdiv_rn(blSum[3*bl],   fbc);
  float gcy = __fdiv_rn(blSum[3*bl+1], fbc);
  float gcz = __fdiv_rn(blSum[3*bl+2], fbc);

  float dx = __fsub_rn(gcx, own.x);
  float dy = __fsub_rn(gcy, own.y);
  float dz = __fsub_rn(gcz, own.z);
  int sgx = (dx > 0.f) ? 1 : ((dx < 0.f) ? -1 : 0);
  int sgy = (dy > 0.f) ? 1 : ((dy < 0.f) ? -1 : 0);
  int sgz = (dz > 0.f) ? 1 : ((dz < 0.f) ? -1 : 0);

  int ax1 = vx + sgx,     ay1 = vy + sgy,     az1 = vz + sgz;
  int ax2 = vx + 2 * sgx, ay2 = vy + 2 * sgy, az2 = vz + 2 * sgz;
  bool v1 = (unsigned)ax1 < (unsigned)VOXD && (unsigned)ay1 < (unsigned)VOXD &&
            (unsigned)az1 < (unsigned)VOXD;
  bool v2 = (unsigned)ax2 < (unsigned)VOXD && (unsigned)ay2 < (unsigned)VOXD &&
            (unsigned)az2 < (unsigned)VOXD;

  float4 q1 = make_float4(0.f, 0.f, 0.f, __int_as_float(-3));
  float4 q2 = q1;
  if (v1) q1 = ctr[voxslot(b, ax1, ay1, az1)];
  if (v2) q2 = ctr[voxslot(b, ax2, ay2, az2)];

  bool hit1 = v1 && (__float_as_int(q1.w) == l);
  bool hit2 = v2 && (__float_as_int(q2.w) == l);
  bool hit = hit1 || hit2;

  float tx = hit1 ? q1.x : (hit2 ? q2.x : gx);
  float ty = hit1 ? q1.y : (hit2 ? q2.y : gy);
  float tz = hit1 ? q1.z : (hit2 ? q2.z : gz);

  tgt[3*i] = tx; tgt[3*i+1] = ty; tgt[3*i+2] = tz;
  if (!purept && !hit) {
    int p = atomicAdd(&sc->missCount, 1);
    missIdx[p] = i;
  } else {
    float tox = __fsub_rn(tx, gx), toy = __fsub_rn(ty, gy), toz = __fsub_rn(tz, gz);
    float ssq = __fadd_rn(__fadd_rn(__fmul_rn(tox,tox), __fmul_rn(toy,toy)),
                          __fmul_rn(toz,toz));
    float m = (ssq > 0.f) ? sqrtf(ssq) : 0.f;
    mag[i] = m;
    atomicAdd(&histHi[__float_as_uint(m) >> 16], 1);
  }
}

// ---------------- K6: fallback — one wave per miss point, persistent grid --------
__global__ void k_fallback(const float* __restrict__ grid, const int* __restrict__ label,
                           const int* __restrict__ batch,
                           const float4* __restrict__ pC,
                           const int* __restrict__ codeBase, const int* __restrict__ codeCnt,
                           const int* __restrict__ missIdx, const Scalars* sc,
                           float* tgt, float* mag, int* histHi) {
  int lane = threadIdx.x & 63;
  int wid = (blockIdx.x * blockDim.x + threadIdx.x) >> 6;
  int nWaves = (gridDim.x * blockDim.x) >> 6;
  int nMiss = sc->missCount;

  for (int t = wid; t < nMiss; t += nWaves) {
    int idx = missIdx[t];
    float gx = grid[3*idx], gy = grid[3*idx+1], gz = grid[3*idx+2];
    float p2 = __fadd_rn(__fadd_rn(__fmul_rn(gx,gx), __fmul_rn(gy,gy)), __fmul_rn(gz,gz));
    int code = batch[idx] * NCLS + label[idx];
    int j0 = codeBase[code];
    int cc = codeCnt[code];

    float bestD = 1e38f;
    int bestJ = -1;
    for (int j = lane; j < cc; j += 64) {
      float4 c = pC[j0 + j];
      float dot = __fadd_rn(__fadd_rn(__fmul_rn(gx,c.x), __fmul_rn(gy,c.y)),
                            __fmul_rn(gz,c.z));
      float d2 = __fadd_rn(__fsub_rn(p2, __fmul_rn(2.0f, dot)), c.w);
      if (d2 < bestD) { bestD = d2; bestJ = j; }
    }
    // lexicographic (d2, j) min across the wave: monotone float key + index
    unsigned fb = __float_as_uint(bestD);
    fb = (fb >> 31) ? ~fb : (fb | 0x80000000u);
    unsigned long long key = ((unsigned long long)fb << 32) | (unsigned)bestJ;
    #pragma unroll
    for (int off = 1; off < 64; off <<= 1) {
      unsigned long long o = __shfl_xor(key, off, 64);
      key = (o < key) ? o : key;
    }
    if (lane == 0) {
      if (cc > 0) {
        int j = (int)(unsigned)(key & 0xFFFFFFFFULL);
        float4 c = pC[j0 + j];
        tgt[3*idx] = c.x; tgt[3*idx+1] = c.y; tgt[3*idx+2] = c.z;
        float tox = __fsub_rn(c.x, gx), toy = __fsub_rn(c.y, gy), toz = __fsub_rn(c.z, gz);
        float ssq = __fadd_rn(__fadd_rn(__fmul_rn(tox,tox), __fmul_rn(toy,toy)),
                              __fmul_rn(toz,toz));
        float m = (ssq > 0.f) ? sqrtf(ssq) : 0.f;
        mag[idx] = m;
        atomicAdd(&histHi[__float_as_uint(m) >> 16], 1);
      } else {
        mag[idx] = 0.f;
        atomicAdd(&histHi[0], 1);
      }
    }
  }
}

// ---------------- K7a: hierarchical select of high bins for ranks r0, r1 ---------
__global__ void __launch_bounds__(1024) k_selbins(const int* histHi, Scalars* sc,
                                                  int r0, int r1) {
  __shared__ int ws[16];
  __shared__ int chunk[2], off[2];
  int tid = threadIdx.x;
  int base = tid * 64;
  int s = 0;
  #pragma unroll 8
  for (int i = 0; i < 64; ++i) s += histHi[base + i];
  int total;
  int incl = block_scan_i(s, ws, &total);
  int lo = incl - s;
  if (r0 >= lo && r0 < incl) { chunk[0] = tid; off[0] = r0 - lo; }
  if (r1 >= lo && r1 < incl) { chunk[1] = tid; off[1] = r1 - lo; }
  __syncthreads();
  int w = tid >> 6, lane = tid & 63;
  if (w < 2) {
    int ch = chunk[w], ofs = off[w];
    int c = histHi[ch * 64 + lane];
    int inc = wave_incl_scan(c);
    if (ofs >= inc - c && ofs < inc) {
      if (w == 0) { sc->binA = ch * 64 + lane; sc->rA = ofs - (inc - c); }
      else        { sc->binB = ch * 64 + lane; sc->rB = ofs - (inc - c); }
    }
  }
}

// ---------------- K7b: low-16-bit histograms within selected bins ----------------
__global__ void k_hist2(const float* mag, const Scalars* sc, int* histA, int* histB, int n) {
  int i = blockIdx.x * blockDim.x + threadIdx.x;
  if (i >= n) return;
  unsigned bits = __float_as_uint(mag[i]);
  int h = (int)(bits >> 16);
  int lo = (int)(bits & 0xFFFFu);
  if (h == sc->binA) atomicAdd(&histA[lo], 1);
  if (h == sc->binB) atomicAdd(&histB[lo], 1);
}

// ---------------- K7c: resolve order statistics + lerp (numpy branch) ------------
__global__ void __launch_bounds__(1024) k_thresh(const int* histA, const int* histB,
                                                 Scalars* sc, double tfrac) {
  __shared__ int ws[16];
  __shared__ int chunkS, offS;
  __shared__ int lowA, lowB;
  int tid = threadIdx.x, lane = tid & 63;
  int rA = sc->rA, rB = sc->rB;
  int binA = sc->binA, binB = sc->binB;

  {
    int s = 0, base = tid * 64;
    #pragma unroll 8
    for (int i = 0; i < 64; ++i) s += histA[base + i];
    int total;
    int incl = block_scan_i(s, ws, &total);
    int lo = incl - s;
    if (rA >= lo && rA < incl) { chunkS = tid; offS = rA - lo; }
    __syncthreads();
    if (tid < 64) {
      int c = histA[chunkS * 64 + lane];
      int inc = wave_incl_scan(c);
      if (offS >= inc - c && offS < inc) lowA = chunkS * 64 + lane;
    }
    __syncthreads();
  }
  {
    int s = 0, base = tid * 64;
    #pragma unroll 8
    for (int i = 0; i < 64; ++i) s += histB[base + i];
    int total;
    int incl = block_scan_i(s, ws, &total);
    int lo = incl - s;
    if (rB >= lo && rB < incl) { chunkS = tid; offS = rB - lo; }
    __syncthreads();
    if (tid < 64) {
      int c = histB[chunkS * 64 + lane];
      int inc = wave_incl_scan(c);
      if (offS >= inc - c && offS < inc) lowB = chunkS * 64 + lane;
    }
    __syncthreads();
  }
  if (tid == 0) {
    unsigned bitsLo = ((unsigned)binA << 16) | (unsigned)lowA;
    unsigned bitsHi = ((unsigned)binB << 16) | (unsigned)lowB;
    double a = (double)__uint_as_float(bitsLo);
    double b = (double)__uint_as_float(bitsHi);
    double t = tfrac;
    double th = (t >= 0.5) ? (b - (b - a) * (1.0 - t)) : (a + (b - a) * t);
    sc->thresh = (float)th;
  }
}

// ---------------- K8: masked huber + cosine reductions ---------------------------
__global__ void k_loss(const float* __restrict__ pred, const float* __restrict__ grid,
                       const float* __restrict__ tgt, const float* __restrict__ mag,
                       Scalars* sc, int n) {
  __shared__ double shH[256];
  __shared__ double shC[256];
  __shared__ int shN[256];
  __shared__ int shM[256];
  int tid = threadIdx.x;
  int i = blockIdx.x * blockDim.x + tid;
  double hub = 0.0, cs = 0.0;
  int c1 = 0, cmd = 0;
  if (i < n) {
    float th = sc->thresh;
    float m = mag[i];
    if (m <= th) {
      c1 = 1;
      float tox = __fsub_rn(tgt[3*i],   grid[3*i]);
      float toy = __fsub_rn(tgt[3*i+1], grid[3*i+1]);
      float toz = __fsub_rn(tgt[3*i+2], grid[3*i+2]);
      float px = pred[3*i], py = pred[3*i+1], pz = pred[3*i+2];
      float d0 = __fsub_rn(px, tox), d1 = __fsub_rn(py, toy), d2 = __fsub_rn(pz, toz);
      float a0 = fabsf(d0), a1 = fabsf(d1), a2 = fabsf(d2);
      float h0 = (a0 < 1.f) ? __fmul_rn(__fmul_rn(0.5f, d0), d0) : __fsub_rn(a0, 0.5f);
      float h1 = (a1 < 1.f) ? __fmul_rn(__fmul_rn(0.5f, d1), d1) : __fsub_rn(a1, 0.5f);
      float h2 = (a2 < 1.f) ? __fmul_rn(__fmul_rn(0.5f, d2), d2) : __fsub_rn(a2, 0.5f);
      hub = (double)h0 + (double)h1 + (double)h2;
      if (m > 0.f) {
        cmd = 1;
        float ps = __fadd_rn(__fadd_rn(__fmul_rn(px,px), __fmul_rn(py,py)), __fmul_rn(pz,pz));
        float pn = (ps > 0.f) ? sqrtf(ps) : 0.f;
        float dotp = __fadd_rn(__fadd_rn(__fmul_rn(px,tox), __fmul_rn(py,toy)),
                               __fmul_rn(pz,toz));
        float den = fmaxf(__fmul_rn(pn, m), 1e-4f);
        cs = (double)__fdiv_rn(dotp, den);
      }
    }
  }
  shH[tid] = hub; shC[tid] = cs; shN[tid] = c1; shM[tid] = cmd;
  __syncthreads();
  for (int off = 128; off > 0; off >>= 1) {
    if (tid < off) {
      shH[tid] += shH[tid+off];
      shC[tid] += shC[tid+off];
      shN[tid] += shN[tid+off];
      shM[tid] += shM[tid+off];
    }
    __syncthreads();
  }
  if (tid == 0) {
    atomicAdd(&sc->hub, shH[0]);
    atomicAdd(&sc->cosSum, shC[0]);
    atomicAdd(&sc->n1, shN[0]);
    atomicAdd(&sc->nmd, shM[0]);
  }
}

// ---------------- K9: finalize ---------------------------------------------------
__global__ void k_final(const Scalars* sc, float* out) {
  double n1 = (double)sc->n1;
  double l1 = (sc->n1 > 0) ? (sc->hub / fmax(n1 * 3.0, 1.0)) : 0.0;
  double nmd = (double)sc->nmd;
  double ld = (sc->nmd > 0) ? (1.0 - sc->cosSum / fmax(nmd, 1.0)) : 0.0;
  out[0] = (float)l1;
  out[1] = (float)ld;
}

extern "C" void kernel_launch(void* const* d_in, const int* in_sizes, int n_in,
                              void* d_out, int out_size, void* d_ws, size_t ws_size,
                              hipStream_t stream) {
  const float* pred  = (const float*)d_in[0];
  const float* grid  = (const float*)d_in[1];
  const int*   label = (const int*)d_in[2];
  const int*   batch = (const int*)d_in[3];
  int n = in_sizes[2];

  char* p = (char*)d_ws;
  auto take = [&](size_t bytes) -> char* {
    char* r = p;
    p += (bytes + 255) & ~(size_t)255;
    return r;
  };
  int*    cnt      = (int*)   take((size_t)SLOTS*4);
  float*  sx       = (float*) take((size_t)SLOTS*4);
  float*  sy       = (float*) take((size_t)SLOTS*4);
  float*  sz       = (float*) take((size_t)SLOTS*4);
  int*    lmask    = (int*)   take((size_t)SLOTS*4);
  float4* ctr      = (float4*)take((size_t)SLOTS*16);
  float4* pC       = (float4*)take((size_t)SLOTS*16);
  int*    blockCnt = (int*)   take((size_t)NBLK*NCODE*4);
  int*    blockBase= (int*)   take((size_t)NBLK*NCODE*4);
  int*    codeBase = (int*)   take(NCODE*4);
  int*    codeCnt  = (int*)   take(NCODE*4);
  int*    blCnt    = (int*)   take(16*4);
  float*  blSum    = (float*) take(48*4);
  int*    hists    = (int*)   take((size_t)3*65536*4);
  float*  tgt      = (float*) take((size_t)n*3*4);
  float*  mag      = (float*) take((size_t)n*4);
  int*    missIdx  = (int*)   take((size_t)n*4);
  Scalars* sc      = (Scalars*)take(sizeof(Scalars));

  int* histHi = hists;
  int* histA  = hists + 65536;
  int* histB  = hists + 131072;

  int nb = (n + 255) / 256;

  k_init<<<768, 256, 0, stream>>>(cnt, sx, sy, sz, lmask, blCnt, blSum, hists, sc);
  k_scatter<<<nb, 256, 0, stream>>>(grid, label, batch, cnt, sx, sy, sz, lmask,
                                    blCnt, blSum, n);
  k_prep<<<NBLK, 256, 0, stream>>>(cnt, sx, sy, sz, lmask, ctr, blockCnt);
  k_bases<<<1, 64, 0, stream>>>(blockCnt, blockBase, codeBase, codeCnt, sc);
  k_compact<<<NBLK, 256, 0, stream>>>(ctr, blockBase, codeBase, pC);
  k_targets<<<nb, 256, 0, stream>>>(grid, label, batch, ctr, blCnt, blSum,
                                    tgt, mag, histHi, missIdx, sc, n);
  k_fallback<<<1024, 256, 0, stream>>>(grid, label, batch, pC, codeBase, codeCnt,
                                       missIdx, sc, tgt, mag, histHi);

  double vi = 0.99 * (double)(n - 1);
  int r0 = (int)vi;
  int r1 = r0 + 1; if (r1 > n - 1) r1 = n - 1;
  double tfrac = vi - (double)r0;

  k_selbins<<<1, 1024, 0, stream>>>(histHi, sc, r0, r1);
  k_hist2<<<nb, 256, 0, stream>>>(mag, sc, histA, histB, n);
  k_thresh<<<1, 1024, 0, stream>>>(histA, histB, sc, tfrac);
  k_loss<<<nb, 256, 0, stream>>>(pred, grid, tgt, mag, sc, n);
  k_final<<<1, 1, 0, stream>>>(sc, (float*)d_out);
}

// Round 5
// 366.746 us; speedup vs baseline: 6.6333x; 1.0178x over previous
//
#include <hip/hip_runtime.h>
#include <climits>

#define VOXD 25
#define SLOT3 (VOXD*VOXD*VOXD)      // 15625
#define SLOTS (2*SLOT3)             // 31250
#define NCLS 8
#define NCODE 16
#define NBLK ((SLOTS + 255) / 256)  // 123

struct Scalars {
  double hub;
  double cosSum;
  int n1;
  int nmd;
  int missCount;
  int nPure;
  int binA, rA, binB, rB;
  float thresh;
  int pad;
};

__device__ __forceinline__ int voxslot(int b, int vx, int vy, int vz) {
  return ((b * VOXD + vx) * VOXD + vy) * VOXD + vz;
}

__device__ __forceinline__ int wave_incl_scan(int v) {
  int lane = threadIdx.x & 63;
  #pragma unroll
  for (int off = 1; off < 64; off <<= 1) {
    int t = __shfl_up(v, off, 64);
    if (lane >= off) v += t;
  }
  return v;
}

// ---- block-wide inclusive scan (int), 1024 threads = 16 waves ----
__device__ __forceinline__ int block_scan_i(int v, int* ws, int* total) {
  int lane = threadIdx.x & 63, w = threadIdx.x >> 6;
  int s = v;
  #pragma unroll
  for (int off = 1; off < 64; off <<= 1) {
    int t = __shfl_up(s, off, 64);
    if (lane >= off) s += t;
  }
  if (lane == 63) ws[w] = s;
  __syncthreads();
  if (threadIdx.x < 16) {
    int x = ws[threadIdx.x];
    #pragma unroll
    for (int off = 1; off < 16; off <<= 1) {
      int t = __shfl_up(x, off, 64);
      if (lane >= off) x += t;
    }
    ws[threadIdx.x] = x;
  }
  __syncthreads();
  if (w > 0) s += ws[w - 1];
  *total = ws[15];
  __syncthreads();
  return s;
}

// ---- 256-thread packed u64 scan (16 codes x 16-bit fields), 4 waves ----
__device__ __forceinline__ void scan4_256(unsigned long long v[4],
                                          unsigned long long* ws /*16*/) {
  int lane = threadIdx.x & 63, w = threadIdx.x >> 6;
  #pragma unroll
  for (int q = 0; q < 4; ++q) {
    unsigned long long s = v[q];
    #pragma unroll
    for (int off = 1; off < 64; off <<= 1) {
      unsigned long long t = __shfl_up(s, off, 64);
      if (lane >= off) s += t;
    }
    v[q] = s;
    if (lane == 63) ws[q * 4 + w] = s;
  }
  __syncthreads();
  if (threadIdx.x < 16) {
    int q = threadIdx.x >> 2, idx = threadIdx.x & 3;
    unsigned long long x = ws[q * 4 + idx];
    #pragma unroll
    for (int off = 1; off < 4; off <<= 1) {
      unsigned long long t = __shfl_up(x, off, 64);
      if (idx >= off) x += t;
    }
    ws[q * 4 + idx] = x;
  }
  __syncthreads();
  #pragma unroll
  for (int q = 0; q < 4; ++q) if (w > 0) v[q] += ws[q * 4 + w - 1];
}

// ---------------- K1: zero-init ----------------
__global__ void k_init(int* cnt, float* sx, float* sy, float* sz, int* lmask,
                       int* blCnt, float* blSum, int* hists, Scalars* sc) {
  int i = blockIdx.x * blockDim.x + threadIdx.x;
  if (i < SLOTS) {
    cnt[i] = 0; sx[i] = 0.f; sy[i] = 0.f; sz[i] = 0.f; lmask[i] = 0;
  }
  if (i < 3 * 65536) hists[i] = 0;
  if (i < 16) { blCnt[i] = 0; blSum[3*i] = 0.f; blSum[3*i+1] = 0.f; blSum[3*i+2] = 0.f; }
  if (i == 0) {
    sc->hub = 0.0; sc->cosSum = 0.0; sc->n1 = 0; sc->nmd = 0;
    sc->missCount = 0; sc->nPure = 0;
  }
}

// ---------------- K2: per-point scatter; label bitmask; LDS-agg (b,l) stats ------
__global__ void k_scatter(const float* __restrict__ grid, const int* __restrict__ label,
                          const int* __restrict__ batch,
                          int* cnt, float* sx, float* sy, float* sz, int* lmask,
                          int* blCnt, float* blSum, int n) {
  __shared__ int sCnt[NCODE];
  __shared__ float sSum[3 * NCODE];
  int tid = threadIdx.x;
  if (tid < NCODE) sCnt[tid] = 0;
  if (tid < 3 * NCODE) sSum[tid] = 0.f;
  __syncthreads();
  int i = blockIdx.x * blockDim.x + tid;
  if (i < n) {
    float gx = grid[3*i], gy = grid[3*i+1], gz = grid[3*i+2];
    int vx = (int)floorf(gx * (1.0f/16.0f));
    int vy = (int)floorf(gy * (1.0f/16.0f));
    int vz = (int)floorf(gz * (1.0f/16.0f));
    int b = batch[i], l = label[i];
    int s = voxslot(b, vx, vy, vz);
    atomicAdd(&cnt[s], 1);
    atomicAdd(&sx[s], gx); atomicAdd(&sy[s], gy); atomicAdd(&sz[s], gz);
    atomicOr(&lmask[s], 1 << l);
    int bl = b * NCLS + l;
    atomicAdd(&sCnt[bl], 1);
    atomicAdd(&sSum[3*bl], gx); atomicAdd(&sSum[3*bl+1], gy); atomicAdd(&sSum[3*bl+2], gz);
  }
  __syncthreads();
  if (tid < NCODE && sCnt[tid] != 0) atomicAdd(&blCnt[tid], sCnt[tid]);
  if (tid < 3 * NCODE && sSum[tid] != 0.f) atomicAdd(&blSum[tid], sSum[tid]);
}

// ---------------- K3a: consolidate slot table to float4 + per-block code counts --
// ctr[s] = {cx, cy, cz, meta}; meta = label if pure, -1 if mixed, -2 if empty.
__global__ void k_prep(const int* cnt, const float* sx, const float* sy, const float* sz,
                       const int* lmask, float4* ctr, int* blockCnt) {
  __shared__ int sc16[NCODE];
  if (threadIdx.x < NCODE) sc16[threadIdx.x] = 0;
  __syncthreads();
  int s = blockIdx.x * 256 + threadIdx.x;
  if (s < SLOTS) {
    int c = cnt[s];
    float4 v = make_float4(0.f, 0.f, 0.f, __int_as_float(-2));
    if (c > 0) {
      float fc = (float)c;
      float cx = __fdiv_rn(sx[s], fc);
      float cy = __fdiv_rn(sy[s], fc);
      float cz = __fdiv_rn(sz[s], fc);
      int m = lmask[s];
      bool pure = (m & (m - 1)) == 0;      // c>0 -> m!=0
      int lbl = __ffs(m) - 1;
      int meta = pure ? lbl : -1;
      v = make_float4(cx, cy, cz, __int_as_float(meta));
      if (pure) atomicAdd(&sc16[(s / SLOT3) * NCLS + lbl], 1);
    }
    ctr[s] = v;
  }
  __syncthreads();
  if (threadIdx.x < NCODE) blockCnt[blockIdx.x * NCODE + threadIdx.x] = sc16[threadIdx.x];
}

// ---------------- K3b: bases per (block,code) and per code -----------------------
__global__ void k_bases(const int* blockCnt, int* blockBase, int* codeBase,
                        int* codeCnt, Scalars* sc) {
  __shared__ int tot[NCODE];
  int c = threadIdx.x;
  if (c < NCODE) {
    int run = 0;
    for (int b = 0; b < NBLK; ++b) {
      blockBase[b * NCODE + c] = run;
      run += blockCnt[b * NCODE + c];
    }
    tot[c] = run;
  }
  __syncthreads();
  if (c == 0) {
    int cum = 0;
    for (int k = 0; k < NCODE; ++k) { codeBase[k] = cum; codeCnt[k] = tot[k]; cum += tot[k]; }
    sc->nPure = cum;
  }
}

// ---------------- K4: compact pure clusters into per-code buckets (float4) -------
// Within-code order == slot order == cluster-rank order -> reference tie-breaks hold.
__global__ void k_compact(const float4* __restrict__ ctr,
                          const int* blockBase, const int* codeBase, float4* pC) {
  __shared__ unsigned long long ws[16];
  int s = blockIdx.x * 256 + threadIdx.x;
  int f = 0, code = 0;
  float4 cv = make_float4(0.f, 0.f, 0.f, 0.f);
  if (s < SLOTS) {
    cv = ctr[s];
    int meta = __float_as_int(cv.w);
    if (meta >= 0) { f = 1; code = (s / SLOT3) * NCLS + meta; }
  }
  unsigned long long v[4] = {0ULL, 0ULL, 0ULL, 0ULL};
  if (f) v[code >> 2] = 1ULL << (16 * (code & 3));
  scan4_256(v, ws);
  if (f) {
    int rank = (int)((v[code >> 2] >> (16 * (code & 3))) & 0xFFFFULL) - 1;
    int pos = codeBase[code] + blockBase[blockIdx.x * NCODE + code] + rank;
    float c2 = __fadd_rn(__fadd_rn(__fmul_rn(cv.x,cv.x), __fmul_rn(cv.y,cv.y)),
                         __fmul_rn(cv.z,cv.z));
    pC[pos] = make_float4(cv.x, cv.y, cv.z, c2);
  }
}

// ---------------- K5: probe targets + wave-aggregated miss list + mag/hist -------
__global__ void k_targets(const float* __restrict__ grid, const int* __restrict__ label,
                          const int* __restrict__ batch,
                          const float4* __restrict__ ctr,
                          const int* __restrict__ blCnt, const float* __restrict__ blSum,
                          float* tgt, float* mag, int* histHi,
                          int* missIdx, Scalars* sc, int n) {
  int i = blockIdx.x * blockDim.x + threadIdx.x;
  int lane = threadIdx.x & 63;
  bool active = (i < n);

  bool miss = false;
  float gx = 0.f, gy = 0.f, gz = 0.f;
  if (active) {
    gx = grid[3*i]; gy = grid[3*i+1]; gz = grid[3*i+2];
    int vx = (int)floorf(gx * (1.0f/16.0f));
    int vy = (int)floorf(gy * (1.0f/16.0f));
    int vz = (int)floorf(gz * (1.0f/16.0f));
    int b = batch[i], l = label[i];
    int s = voxslot(b, vx, vy, vz);

    float4 own = ctr[s];
    bool purept = (__float_as_int(own.w) >= 0);

    int bl = b * NCLS + l;
    float fbc = (float)max(blCnt[bl], 1);
    float gcx = __fdiv_rn(blSum[3*bl],   fbc);
    float gcy = __fdiv_rn(blSum[3*bl+1], fbc);
    float gcz = __fdiv_rn(blSum[3*bl+2], fbc);

    float dx = __fsub_rn(gcx, own.x);
    float dy = __fsub_rn(gcy, own.y);
    float dz = __fsub_rn(gcz, own.z);
    int sgx = (dx > 0.f) ? 1 : ((dx < 0.f) ? -1 : 0);
    int sgy = (dy > 0.f) ? 1 : ((dy < 0.f) ? -1 : 0);
    int sgz = (dz > 0.f) ? 1 : ((dz < 0.f) ? -1 : 0);

    int ax1 = vx + sgx,     ay1 = vy + sgy,     az1 = vz + sgz;
    int ax2 = vx + 2 * sgx, ay2 = vy + 2 * sgy, az2 = vz + 2 * sgz;
    bool v1 = (unsigned)ax1 < (unsigned)VOXD && (unsigned)ay1 < (unsigned)VOXD &&
              (unsigned)az1 < (unsigned)VOXD;
    bool v2 = (unsigned)ax2 < (unsigned)VOXD && (unsigned)ay2 < (unsigned)VOXD &&
              (unsigned)az2 < (unsigned)VOXD;

    float4 q1 = make_float4(0.f, 0.f, 0.f, __int_as_float(-3));
    float4 q2 = q1;
    if (v1) q1 = ctr[voxslot(b, ax1, ay1, az1)];
    if (v2) q2 = ctr[voxslot(b, ax2, ay2, az2)];

    bool hit1 = v1 && (__float_as_int(q1.w) == l);
    bool hit2 = v2 && (__float_as_int(q2.w) == l);
    bool hit = hit1 || hit2;

    float tx = hit1 ? q1.x : (hit2 ? q2.x : gx);
    float ty = hit1 ? q1.y : (hit2 ? q2.y : gy);
    float tz = hit1 ? q1.z : (hit2 ? q2.z : gz);

    tgt[3*i] = tx; tgt[3*i+1] = ty; tgt[3*i+2] = tz;
    miss = (!purept && !hit);
    if (!miss) {
      float tox = __fsub_rn(tx, gx), toy = __fsub_rn(ty, gy), toz = __fsub_rn(tz, gz);
      float ssq = __fadd_rn(__fadd_rn(__fmul_rn(tox,tox), __fmul_rn(toy,toy)),
                            __fmul_rn(toz,toz));
      float m = (ssq > 0.f) ? sqrtf(ssq) : 0.f;
      mag[i] = m;
      atomicAdd(&histHi[__float_as_uint(m) >> 16], 1);
    }
  }
  // wave-aggregated append: one atomic per wave instead of one per miss thread
  unsigned long long mb = __ballot(miss);
  int mcnt = __popcll(mb);
  int base = 0;
  if (lane == 0 && mcnt > 0) base = atomicAdd(&sc->missCount, mcnt);
  base = __shfl(base, 0, 64);
  if (miss) {
    int pos = base + __popcll(mb & ((1ULL << lane) - 1ULL));
    missIdx[pos] = i;
  }
}

// ---------------- K6: fallback — one wave per miss point, persistent grid --------
__global__ void k_fallback(const float* __restrict__ grid, const int* __restrict__ label,
                           const int* __restrict__ batch,
                           const float4* __restrict__ pC,
                           const int* __restrict__ codeBase, const int* __restrict__ codeCnt,
                           const int* __restrict__ missIdx, const Scalars* sc,
                           float* tgt, float* mag, int* histHi) {
  int lane = threadIdx.x & 63;
  int wid = (blockIdx.x * blockDim.x + threadIdx.x) >> 6;
  int nWaves = (gridDim.x * blockDim.x) >> 6;
  int nMiss = sc->missCount;

  for (int t = wid; t < nMiss; t += nWaves) {
    int idx = missIdx[t];
    float gx = grid[3*idx], gy = grid[3*idx+1], gz = grid[3*idx+2];
    float p2 = __fadd_rn(__fadd_rn(__fmul_rn(gx,gx), __fmul_rn(gy,gy)), __fmul_rn(gz,gz));
    int code = batch[idx] * NCLS + label[idx];
    int j0 = codeBase[code];
    int cc = codeCnt[code];

    float bestD = 1e38f;
    int bestJ = -1;
    for (int j = lane; j < cc; j += 64) {
      float4 c = pC[j0 + j];
      float dot = __fadd_rn(__fadd_rn(__fmul_rn(gx,c.x), __fmul_rn(gy,c.y)),
                            __fmul_rn(gz,c.z));
      float d2 = __fadd_rn(__fsub_rn(p2, __fmul_rn(2.0f, dot)), c.w);
      if (d2 < bestD) { bestD = d2; bestJ = j; }
    }
    // lexicographic (d2, j) min across the wave: monotone float key + index
    unsigned fb = __float_as_uint(bestD);
    fb = (fb >> 31) ? ~fb : (fb | 0x80000000u);
    unsigned long long key = ((unsigned long long)fb << 32) | (unsigned)bestJ;
    #pragma unroll
    for (int off = 1; off < 64; off <<= 1) {
      unsigned long long o = __shfl_xor(key, off, 64);
      key = (o < key) ? o : key;
    }
    if (lane == 0) {
      if (cc > 0) {
        int j = (int)(unsigned)(key & 0xFFFFFFFFULL);
        float4 c = pC[j0 + j];
        tgt[3*idx] = c.x; tgt[3*idx+1] = c.y; tgt[3*idx+2] = c.z;
        float tox = __fsub_rn(c.x, gx), toy = __fsub_rn(c.y, gy), toz = __fsub_rn(c.z, gz);
        float ssq = __fadd_rn(__fadd_rn(__fmul_rn(tox,tox), __fmul_rn(toy,toy)),
                              __fmul_rn(toz,toz));
        float m = (ssq > 0.f) ? sqrtf(ssq) : 0.f;
        mag[idx] = m;
        atomicAdd(&histHi[__float_as_uint(m) >> 16], 1);
      } else {
        mag[idx] = 0.f;
        atomicAdd(&histHi[0], 1);
      }
    }
  }
}

// ---------------- K7a: hierarchical select of high bins for ranks r0, r1 ---------
__global__ void __launch_bounds__(1024) k_selbins(const int* histHi, Scalars* sc,
                                                  int r0, int r1) {
  __shared__ int ws[16];
  __shared__ int chunk[2], off[2];
  int tid = threadIdx.x;
  int base = tid * 64;
  int s = 0;
  #pragma unroll 8
  for (int i = 0; i < 64; ++i) s += histHi[base + i];
  int total;
  int incl = block_scan_i(s, ws, &total);
  int lo = incl - s;
  if (r0 >= lo && r0 < incl) { chunk[0] = tid; off[0] = r0 - lo; }
  if (r1 >= lo && r1 < incl) { chunk[1] = tid; off[1] = r1 - lo; }
  __syncthreads();
  int w = tid >> 6, lane = tid & 63;
  if (w < 2) {
    int ch = chunk[w], ofs = off[w];
    int c = histHi[ch * 64 + lane];
    int inc = wave_incl_scan(c);
    if (ofs >= inc - c && ofs < inc) {
      if (w == 0) { sc->binA = ch * 64 + lane; sc->rA = ofs - (inc - c); }
      else        { sc->binB = ch * 64 + lane; sc->rB = ofs - (inc - c); }
    }
  }
}

// ---------------- K7b: low-16-bit histograms within selected bins ----------------
__global__ void k_hist2(const float* mag, const Scalars* sc, int* histA, int* histB, int n) {
  int i = blockIdx.x * blockDim.x + threadIdx.x;
  if (i >= n) return;
  unsigned bits = __float_as_uint(mag[i]);
  int h = (int)(bits >> 16);
  int lo = (int)(bits & 0xFFFFu);
  if (h == sc->binA) atomicAdd(&histA[lo], 1);
  if (h == sc->binB) atomicAdd(&histB[lo], 1);
}

// ---------------- K7c: resolve order statistics + lerp (numpy branch) ------------
__global__ void __launch_bounds__(1024) k_thresh(const int* histA, const int* histB,
                                                 Scalars* sc, double tfrac) {
  __shared__ int ws[16];
  __shared__ int chunkS, offS;
  __shared__ int lowA, lowB;
  int tid = threadIdx.x, lane = tid & 63;
  int rA = sc->rA, rB = sc->rB;
  int binA = sc->binA, binB = sc->binB;

  {
    int s = 0, base = tid * 64;
    #pragma unroll 8
    for (int i = 0; i < 64; ++i) s += histA[base + i];
    int total;
    int incl = block_scan_i(s, ws, &total);
    int lo = incl - s;
    if (rA >= lo && rA < incl) { chunkS = tid; offS = rA - lo; }
    __syncthreads();
    if (tid < 64) {
      int c = histA[chunkS * 64 + lane];
      int inc = wave_incl_scan(c);
      if (offS >= inc - c && offS < inc) lowA = chunkS * 64 + lane;
    }
    __syncthreads();
  }
  {
    int s = 0, base = tid * 64;
    #pragma unroll 8
    for (int i = 0; i < 64; ++i) s += histB[base + i];
    int total;
    int incl = block_scan_i(s, ws, &total);
    int lo = incl - s;
    if (rB >= lo && rB < incl) { chunkS = tid; offS = rB - lo; }
    __syncthreads();
    if (tid < 64) {
      int c = histB[chunkS * 64 + lane];
      int inc = wave_incl_scan(c);
      if (offS >= inc - c && offS < inc) lowB = chunkS * 64 + lane;
    }
    __syncthreads();
  }
  if (tid == 0) {
    unsigned bitsLo = ((unsigned)binA << 16) | (unsigned)lowA;
    unsigned bitsHi = ((unsigned)binB << 16) | (unsigned)lowB;
    double a = (double)__uint_as_float(bitsLo);
    double b = (double)__uint_as_float(bitsHi);
    double t = tfrac;
    double th = (t >= 0.5) ? (b - (b - a) * (1.0 - t)) : (a + (b - a) * t);
    sc->thresh = (float)th;
  }
}

// ---------------- K8: masked huber + cosine reductions ---------------------------
__global__ void k_loss(const float* __restrict__ pred, const float* __restrict__ grid,
                       const float* __restrict__ tgt, const float* __restrict__ mag,
                       Scalars* sc, int n) {
  __shared__ double shH[256];
  __shared__ double shC[256];
  __shared__ int shN[256];
  __shared__ int shM[256];
  int tid = threadIdx.x;
  int i = blockIdx.x * blockDim.x + tid;
  double hub = 0.0, cs = 0.0;
  int c1 = 0, cmd = 0;
  if (i < n) {
    float th = sc->thresh;
    float m = mag[i];
    if (m <= th) {
      c1 = 1;
      float tox = __fsub_rn(tgt[3*i],   grid[3*i]);
      float toy = __fsub_rn(tgt[3*i+1], grid[3*i+1]);
      float toz = __fsub_rn(tgt[3*i+2], grid[3*i+2]);
      float px = pred[3*i], py = pred[3*i+1], pz = pred[3*i+2];
      float d0 = __fsub_rn(px, tox), d1 = __fsub_rn(py, toy), d2 = __fsub_rn(pz, toz);
      float a0 = fabsf(d0), a1 = fabsf(d1), a2 = fabsf(d2);
      float h0 = (a0 < 1.f) ? __fmul_rn(__fmul_rn(0.5f, d0), d0) : __fsub_rn(a0, 0.5f);
      float h1 = (a1 < 1.f) ? __fmul_rn(__fmul_rn(0.5f, d1), d1) : __fsub_rn(a1, 0.5f);
      float h2 = (a2 < 1.f) ? __fmul_rn(__fmul_rn(0.5f, d2), d2) : __fsub_rn(a2, 0.5f);
      hub = (double)h0 + (double)h1 + (double)h2;
      if (m > 0.f) {
        cmd = 1;
        float ps = __fadd_rn(__fadd_rn(__fmul_rn(px,px), __fmul_rn(py,py)), __fmul_rn(pz,pz));
        float pn = (ps > 0.f) ? sqrtf(ps) : 0.f;
        float dotp = __fadd_rn(__fadd_rn(__fmul_rn(px,tox), __fmul_rn(py,toy)),
                               __fmul_rn(pz,toz));
        float den = fmaxf(__fmul_rn(pn, m), 1e-4f);
        cs = (double)__fdiv_rn(dotp, den);
      }
    }
  }
  shH[tid] = hub; shC[tid] = cs; shN[tid] = c1; shM[tid] = cmd;
  __syncthreads();
  for (int off = 128; off > 0; off >>= 1) {
    if (tid < off) {
      shH[tid] += shH[tid+off];
      shC[tid] += shC[tid+off];
      shN[tid] += shN[tid+off];
      shM[tid] += shM[tid+off];
    }
    __syncthreads();
  }
  if (tid == 0) {
    atomicAdd(&sc->hub, shH[0]);
    atomicAdd(&sc->cosSum, shC[0]);
    atomicAdd(&sc->n1, shN[0]);
    atomicAdd(&sc->nmd, shM[0]);
  }
}

// ---------------- K9: finalize ---------------------------------------------------
__global__ void k_final(const Scalars* sc, float* out) {
  double n1 = (double)sc->n1;
  double l1 = (sc->n1 > 0) ? (sc->hub / fmax(n1 * 3.0, 1.0)) : 0.0;
  double nmd = (double)sc->nmd;
  double ld = (sc->nmd > 0) ? (1.0 - sc->cosSum / fmax(nmd, 1.0)) : 0.0;
  out[0] = (float)l1;
  out[1] = (float)ld;
}

extern "C" void kernel_launch(void* const* d_in, const int* in_sizes, int n_in,
                              void* d_out, int out_size, void* d_ws, size_t ws_size,
                              hipStream_t stream) {
  const float* pred  = (const float*)d_in[0];
  const float* grid  = (const float*)d_in[1];
  const int*   label = (const int*)d_in[2];
  const int*   batch = (const int*)d_in[3];
  int n = in_sizes[2];

  char* p = (char*)d_ws;
  auto take = [&](size_t bytes) -> char* {
    char* r = p;
    p += (bytes + 255) & ~(size_t)255;
    return r;
  };
  int*    cnt      = (int*)   take((size_t)SLOTS*4);
  float*  sx       = (float*) take((size_t)SLOTS*4);
  float*  sy       = (float*) take((size_t)SLOTS*4);
  float*  sz       = (float*) take((size_t)SLOTS*4);
  int*    lmask    = (int*)   take((size_t)SLOTS*4);
  float4* ctr      = (float4*)take((size_t)SLOTS*16);
  float4* pC       = (float4*)take((size_t)SLOTS*16);
  int*    blockCnt = (int*)   take((size_t)NBLK*NCODE*4);
  int*    blockBase= (int*)   take((size_t)NBLK*NCODE*4);
  int*    codeBase = (int*)   take(NCODE*4);
  int*    codeCnt  = (int*)   take(NCODE*4);
  int*    blCnt    = (int*)   take(16*4);
  float*  blSum    = (float*) take(48*4);
  int*    hists    = (int*)   take((size_t)3*65536*4);
  float*  tgt      = (float*) take((size_t)n*3*4);
  float*  mag      = (float*) take((size_t)n*4);
  int*    missIdx  = (int*)   take((size_t)n*4);
  Scalars* sc      = (Scalars*)take(sizeof(Scalars));

  int* histHi = hists;
  int* histA  = hists + 65536;
  int* histB  = hists + 131072;

  int nb = (n + 255) / 256;

  k_init<<<768, 256, 0, stream>>>(cnt, sx, sy, sz, lmask, blCnt, blSum, hists, sc);
  k_scatter<<<nb, 256, 0, stream>>>(grid, label, batch, cnt, sx, sy, sz, lmask,
                                    blCnt, blSum, n);
  k_prep<<<NBLK, 256, 0, stream>>>(cnt, sx, sy, sz, lmask, ctr, blockCnt);
  k_bases<<<1, 64, 0, stream>>>(blockCnt, blockBase, codeBase, codeCnt, sc);
  k_compact<<<NBLK, 256, 0, stream>>>(ctr, blockBase, codeBase, pC);
  k_targets<<<nb, 256, 0, stream>>>(grid, label, batch, ctr, blCnt, blSum,
                                    tgt, mag, histHi, missIdx, sc, n);
  k_fallback<<<1024, 256, 0, stream>>>(grid, label, batch, pC, codeBase, codeCnt,
                                       missIdx, sc, tgt, mag, histHi);

  double vi = 0.99 * (double)(n - 1);
  int r0 = (int)vi;
  int r1 = r0 + 1; if (r1 > n - 1) r1 = n - 1;
  double tfrac = vi - (double)r0;

  k_selbins<<<1, 1024, 0, stream>>>(histHi, sc, r0, r1);
  k_hist2<<<nb, 256, 0, stream>>>(mag, sc, histA, histB, n);
  k_thresh<<<1, 1024, 0, stream>>>(histA, histB, sc, tfrac);
  k_loss<<<nb, 256, 0, stream>>>(pred, grid, tgt, mag, sc, n);
  k_final<<<1, 1, 0, stream>>>(sc, (float*)d_out);
}

// Round 6
// 281.425 us; speedup vs baseline: 8.6444x; 1.3032x over previous
//
#include <hip/hip_runtime.h>
#include <climits>

#define VOXD 25
#define SLOT3 (VOXD*VOXD*VOXD)      // 15625
#define SLOTS (2*SLOT3)             // 31250
#define NCLS 8
#define NCODE 16
#define NBLK ((SLOTS + 255) / 256)  // 123

struct Scalars {
  double hub;
  double cosSum;
  int n1;
  int nmd;
  int missCount;
  int nPure;
  int binA, rA, binB, rB;
  float thresh;
  int pad;
};

__device__ __forceinline__ int voxslot(int b, int vx, int vy, int vz) {
  return ((b * VOXD + vx) * VOXD + vy) * VOXD + vz;
}

__device__ __forceinline__ int wave_incl_scan(int v) {
  int lane = threadIdx.x & 63;
  #pragma unroll
  for (int off = 1; off < 64; off <<= 1) {
    int t = __shfl_up(v, off, 64);
    if (lane >= off) v += t;
  }
  return v;
}

// ---- block-wide inclusive scan (int), 1024 threads = 16 waves ----
__device__ __forceinline__ int block_scan_i(int v, int* ws, int* total) {
  int lane = threadIdx.x & 63, w = threadIdx.x >> 6;
  int s = v;
  #pragma unroll
  for (int off = 1; off < 64; off <<= 1) {
    int t = __shfl_up(s, off, 64);
    if (lane >= off) s += t;
  }
  if (lane == 63) ws[w] = s;
  __syncthreads();
  if (threadIdx.x < 16) {
    int x = ws[threadIdx.x];
    #pragma unroll
    for (int off = 1; off < 16; off <<= 1) {
      int t = __shfl_up(x, off, 64);
      if (lane >= off) x += t;
    }
    ws[threadIdx.x] = x;
  }
  __syncthreads();
  if (w > 0) s += ws[w - 1];
  *total = ws[15];
  __syncthreads();
  return s;
}

// ---- 256-thread packed u64 scan (16 codes x 16-bit fields), 4 waves ----
__device__ __forceinline__ void scan4_256(unsigned long long v[4],
                                          unsigned long long* ws /*16*/) {
  int lane = threadIdx.x & 63, w = threadIdx.x >> 6;
  #pragma unroll
  for (int q = 0; q < 4; ++q) {
    unsigned long long s = v[q];
    #pragma unroll
    for (int off = 1; off < 64; off <<= 1) {
      unsigned long long t = __shfl_up(s, off, 64);
      if (lane >= off) s += t;
    }
    v[q] = s;
    if (lane == 63) ws[q * 4 + w] = s;
  }
  __syncthreads();
  if (threadIdx.x < 16) {
    int q = threadIdx.x >> 2, idx = threadIdx.x & 3;
    unsigned long long x = ws[q * 4 + idx];
    #pragma unroll
    for (int off = 1; off < 4; off <<= 1) {
      unsigned long long t = __shfl_up(x, off, 64);
      if (idx >= off) x += t;
    }
    ws[q * 4 + idx] = x;
  }
  __syncthreads();
  #pragma unroll
  for (int q = 0; q < 4; ++q) if (w > 0) v[q] += ws[q * 4 + w - 1];
}

// ---------------- K1: zero-init ----------------
__global__ void k_init(int* cnt, float* sx, float* sy, float* sz, int* lmask,
                       int* blCnt, float* blSum, int* hists, Scalars* sc) {
  int i = blockIdx.x * blockDim.x + threadIdx.x;
  if (i < SLOTS) {
    cnt[i] = 0; sx[i] = 0.f; sy[i] = 0.f; sz[i] = 0.f; lmask[i] = 0;
  }
  if (i < 3 * 65536) hists[i] = 0;
  if (i < 16) { blCnt[i] = 0; blSum[3*i] = 0.f; blSum[3*i+1] = 0.f; blSum[3*i+2] = 0.f; }
  if (i == 0) {
    sc->hub = 0.0; sc->cosSum = 0.0; sc->n1 = 0; sc->nmd = 0;
    sc->missCount = 0; sc->nPure = 0;
  }
}

// ---------------- K2: per-point scatter; label bitmask; LDS-agg (b,l) stats ------
__global__ void k_scatter(const float* __restrict__ grid, const int* __restrict__ label,
                          const int* __restrict__ batch,
                          int* cnt, float* sx, float* sy, float* sz, int* lmask,
                          int* blCnt, float* blSum, int n) {
  __shared__ int sCnt[NCODE];
  __shared__ float sSum[3 * NCODE];
  int tid = threadIdx.x;
  if (tid < NCODE) sCnt[tid] = 0;
  if (tid < 3 * NCODE) sSum[tid] = 0.f;
  __syncthreads();
  int i = blockIdx.x * blockDim.x + tid;
  if (i < n) {
    float gx = grid[3*i], gy = grid[3*i+1], gz = grid[3*i+2];
    int vx = (int)floorf(gx * (1.0f/16.0f));
    int vy = (int)floorf(gy * (1.0f/16.0f));
    int vz = (int)floorf(gz * (1.0f/16.0f));
    int b = batch[i], l = label[i];
    int s = voxslot(b, vx, vy, vz);
    atomicAdd(&cnt[s], 1);
    atomicAdd(&sx[s], gx); atomicAdd(&sy[s], gy); atomicAdd(&sz[s], gz);
    atomicOr(&lmask[s], 1 << l);
    int bl = b * NCLS + l;
    atomicAdd(&sCnt[bl], 1);
    atomicAdd(&sSum[3*bl], gx); atomicAdd(&sSum[3*bl+1], gy); atomicAdd(&sSum[3*bl+2], gz);
  }
  __syncthreads();
  if (tid < NCODE && sCnt[tid] != 0) atomicAdd(&blCnt[tid], sCnt[tid]);
  if (tid < 3 * NCODE && sSum[tid] != 0.f) atomicAdd(&blSum[tid], sSum[tid]);
}

// ---------------- K3a: consolidate slot table to float4 + per-block code counts --
// ctr[s] = {cx, cy, cz, meta}; meta = label if pure, -1 if mixed, -2 if empty.
__global__ void k_prep(const int* cnt, const float* sx, const float* sy, const float* sz,
                       const int* lmask, float4* ctr, int* blockCnt) {
  __shared__ int sc16[NCODE];
  if (threadIdx.x < NCODE) sc16[threadIdx.x] = 0;
  __syncthreads();
  int s = blockIdx.x * 256 + threadIdx.x;
  if (s < SLOTS) {
    int c = cnt[s];
    float4 v = make_float4(0.f, 0.f, 0.f, __int_as_float(-2));
    if (c > 0) {
      float fc = (float)c;
      float cx = __fdiv_rn(sx[s], fc);
      float cy = __fdiv_rn(sy[s], fc);
      float cz = __fdiv_rn(sz[s], fc);
      int m = lmask[s];
      bool pure = (m & (m - 1)) == 0;      // c>0 -> m!=0
      int lbl = __ffs(m) - 1;
      int meta = pure ? lbl : -1;
      v = make_float4(cx, cy, cz, __int_as_float(meta));
      if (pure) atomicAdd(&sc16[(s / SLOT3) * NCLS + lbl], 1);
    }
    ctr[s] = v;
  }
  __syncthreads();
  if (threadIdx.x < NCODE) blockCnt[blockIdx.x * NCODE + threadIdx.x] = sc16[threadIdx.x];
}

// ---------------- K3b: bases per (block,code) and per code -----------------------
__global__ void k_bases(const int* blockCnt, int* blockBase, int* codeBase,
                        int* codeCnt, Scalars* sc) {
  __shared__ int tot[NCODE];
  int c = threadIdx.x;
  if (c < NCODE) {
    int run = 0;
    for (int b = 0; b < NBLK; ++b) {
      blockBase[b * NCODE + c] = run;
      run += blockCnt[b * NCODE + c];
    }
    tot[c] = run;
  }
  __syncthreads();
  if (c == 0) {
    int cum = 0;
    for (int k = 0; k < NCODE; ++k) { codeBase[k] = cum; codeCnt[k] = tot[k]; cum += tot[k]; }
    sc->nPure = cum;
  }
}

// ---------------- K4: compact pure clusters into per-code buckets (float4) -------
// Within-code order == slot order == cluster-rank order -> reference tie-breaks hold.
__global__ void k_compact(const float4* __restrict__ ctr,
                          const int* blockBase, const int* codeBase, float4* pC) {
  __shared__ unsigned long long ws[16];
  int s = blockIdx.x * 256 + threadIdx.x;
  int f = 0, code = 0;
  float4 cv = make_float4(0.f, 0.f, 0.f, 0.f);
  if (s < SLOTS) {
    cv = ctr[s];
    int meta = __float_as_int(cv.w);
    if (meta >= 0) { f = 1; code = (s / SLOT3) * NCLS + meta; }
  }
  unsigned long long v[4] = {0ULL, 0ULL, 0ULL, 0ULL};
  if (f) v[code >> 2] = 1ULL << (16 * (code & 3));
  scan4_256(v, ws);
  if (f) {
    int rank = (int)((v[code >> 2] >> (16 * (code & 3))) & 0xFFFFULL) - 1;
    int pos = codeBase[code] + blockBase[blockIdx.x * NCODE + code] + rank;
    float c2 = __fadd_rn(__fadd_rn(__fmul_rn(cv.x,cv.x), __fmul_rn(cv.y,cv.y)),
                         __fmul_rn(cv.z,cv.z));
    pC[pos] = make_float4(cv.x, cv.y, cv.z, c2);
  }
}

// ---------------- K5: probe targets, NO per-point atomics ------------------------
// Writes tgt + mag (non-miss); miss list via block-aggregated append (1 atomic/blk).
__global__ void k_targets(const float* __restrict__ grid, const int* __restrict__ label,
                          const int* __restrict__ batch,
                          const float4* __restrict__ ctr,
                          const int* __restrict__ blCnt, const float* __restrict__ blSum,
                          float* tgt, float* mag,
                          int* missIdx, Scalars* sc, int n) {
  __shared__ int wcnt[4];
  __shared__ int sbase;
  int tid = threadIdx.x, lane = tid & 63, w = tid >> 6;
  int i = blockIdx.x * blockDim.x + tid;
  bool active = (i < n);
  bool miss = false;

  if (active) {
    float gx = grid[3*i], gy = grid[3*i+1], gz = grid[3*i+2];
    int vx = (int)floorf(gx * (1.0f/16.0f));
    int vy = (int)floorf(gy * (1.0f/16.0f));
    int vz = (int)floorf(gz * (1.0f/16.0f));
    int b = batch[i], l = label[i];
    int s = voxslot(b, vx, vy, vz);

    float4 own = ctr[s];
    bool purept = (__float_as_int(own.w) >= 0);

    int bl = b * NCLS + l;
    float fbc = (float)max(blCnt[bl], 1);
    float gcx = __fdiv_rn(blSum[3*bl],   fbc);
    float gcy = __fdiv_rn(blSum[3*bl+1], fbc);
    float gcz = __fdiv_rn(blSum[3*bl+2], fbc);

    float dx = __fsub_rn(gcx, own.x);
    float dy = __fsub_rn(gcy, own.y);
    float dz = __fsub_rn(gcz, own.z);
    int sgx = (dx > 0.f) ? 1 : ((dx < 0.f) ? -1 : 0);
    int sgy = (dy > 0.f) ? 1 : ((dy < 0.f) ? -1 : 0);
    int sgz = (dz > 0.f) ? 1 : ((dz < 0.f) ? -1 : 0);

    int ax1 = vx + sgx,     ay1 = vy + sgy,     az1 = vz + sgz;
    int ax2 = vx + 2 * sgx, ay2 = vy + 2 * sgy, az2 = vz + 2 * sgz;
    bool v1 = (unsigned)ax1 < (unsigned)VOXD && (unsigned)ay1 < (unsigned)VOXD &&
              (unsigned)az1 < (unsigned)VOXD;
    bool v2 = (unsigned)ax2 < (unsigned)VOXD && (unsigned)ay2 < (unsigned)VOXD &&
              (unsigned)az2 < (unsigned)VOXD;

    float4 q1 = make_float4(0.f, 0.f, 0.f, __int_as_float(-3));
    float4 q2 = q1;
    if (v1) q1 = ctr[voxslot(b, ax1, ay1, az1)];
    if (v2) q2 = ctr[voxslot(b, ax2, ay2, az2)];

    bool hit1 = v1 && (__float_as_int(q1.w) == l);
    bool hit2 = v2 && (__float_as_int(q2.w) == l);
    bool hit = hit1 || hit2;

    float tx = hit1 ? q1.x : (hit2 ? q2.x : gx);
    float ty = hit1 ? q1.y : (hit2 ? q2.y : gy);
    float tz = hit1 ? q1.z : (hit2 ? q2.z : gz);

    tgt[3*i] = tx; tgt[3*i+1] = ty; tgt[3*i+2] = tz;
    miss = (!purept && !hit);
    if (!miss) {
      float tox = __fsub_rn(tx, gx), toy = __fsub_rn(ty, gy), toz = __fsub_rn(tz, gz);
      float ssq = __fadd_rn(__fadd_rn(__fmul_rn(tox,tox), __fmul_rn(toy,toy)),
                            __fmul_rn(toz,toz));
      float m = (ssq > 0.f) ? sqrtf(ssq) : 0.f;
      mag[i] = m;
    }
  }
  // block-aggregated miss append: exactly one global atomic per block
  unsigned long long mb = __ballot(miss);
  int mc = __popcll(mb);
  if (lane == 0) wcnt[w] = mc;
  __syncthreads();
  if (tid == 0) {
    int tot = wcnt[0] + wcnt[1] + wcnt[2] + wcnt[3];
    sbase = (tot > 0) ? atomicAdd(&sc->missCount, tot) : 0;
  }
  __syncthreads();
  if (miss) {
    int base = sbase;
    for (int q = 0; q < 4; ++q) if (q < w) base += wcnt[q];
    int pos = base + __popcll(mb & ((1ULL << lane) - 1ULL));
    missIdx[pos] = i;
  }
}

// ---------------- K6: fallback — one wave per miss point; writes mag only --------
__global__ void k_fallback(const float* __restrict__ grid, const int* __restrict__ label,
                           const int* __restrict__ batch,
                           const float4* __restrict__ pC,
                           const int* __restrict__ codeBase, const int* __restrict__ codeCnt,
                           const int* __restrict__ missIdx, const Scalars* sc,
                           float* tgt, float* mag) {
  int lane = threadIdx.x & 63;
  int wid = (blockIdx.x * blockDim.x + threadIdx.x) >> 6;
  int nWaves = (gridDim.x * blockDim.x) >> 6;
  int nMiss = sc->missCount;

  for (int t = wid; t < nMiss; t += nWaves) {
    int idx = missIdx[t];
    float gx = grid[3*idx], gy = grid[3*idx+1], gz = grid[3*idx+2];
    float p2 = __fadd_rn(__fadd_rn(__fmul_rn(gx,gx), __fmul_rn(gy,gy)), __fmul_rn(gz,gz));
    int code = batch[idx] * NCLS + label[idx];
    int j0 = codeBase[code];
    int cc = codeCnt[code];

    float bestD = 1e38f;
    int bestJ = -1;
    for (int j = lane; j < cc; j += 64) {
      float4 c = pC[j0 + j];
      float dot = __fadd_rn(__fadd_rn(__fmul_rn(gx,c.x), __fmul_rn(gy,c.y)),
                            __fmul_rn(gz,c.z));
      float d2 = __fadd_rn(__fsub_rn(p2, __fmul_rn(2.0f, dot)), c.w);
      if (d2 < bestD) { bestD = d2; bestJ = j; }
    }
    // lexicographic (d2, j) min across the wave: monotone float key + index
    unsigned fb = __float_as_uint(bestD);
    fb = (fb >> 31) ? ~fb : (fb | 0x80000000u);
    unsigned long long key = ((unsigned long long)fb << 32) | (unsigned)bestJ;
    #pragma unroll
    for (int off = 1; off < 64; off <<= 1) {
      unsigned long long o = __shfl_xor(key, off, 64);
      key = (o < key) ? o : key;
    }
    if (lane == 0) {
      if (cc > 0) {
        int j = (int)(unsigned)(key & 0xFFFFFFFFULL);
        float4 c = pC[j0 + j];
        tgt[3*idx] = c.x; tgt[3*idx+1] = c.y; tgt[3*idx+2] = c.z;
        float tox = __fsub_rn(c.x, gx), toy = __fsub_rn(c.y, gy), toz = __fsub_rn(c.z, gz);
        float ssq = __fadd_rn(__fadd_rn(__fmul_rn(tox,tox), __fmul_rn(toy,toy)),
                              __fmul_rn(toz,toz));
        mag[idx] = (ssq > 0.f) ? sqrtf(ssq) : 0.f;
      } else {
        mag[idx] = 0.f;
      }
    }
  }
}

// ---------------- K6b: high-16-bit histogram with wave same-bin dedup ------------
__global__ void k_hista(const float* __restrict__ mag, int* histHi, int n) {
  int i = blockIdx.x * blockDim.x + threadIdx.x;
  int lane = threadIdx.x & 63;
  unsigned bin = 0xFFFFFFFFu;
  if (i < n) bin = __float_as_uint(mag[i]) >> 16;
  unsigned long long act = __ballot(i < n);
  while (act) {
    int leader = (int)(__ffsll((long long)act) - 1);
    unsigned b0 = (unsigned)__shfl((int)bin, leader, 64);
    unsigned long long same = __ballot(bin == b0) & act;
    if (lane == leader) atomicAdd(&histHi[b0], __popcll(same));
    act &= ~same;
  }
}

// ---------------- K7a: hierarchical select of high bins for ranks r0, r1 ---------
__global__ void __launch_bounds__(1024) k_selbins(const int* histHi, Scalars* sc,
                                                  int r0, int r1) {
  __shared__ int ws[16];
  __shared__ int chunk[2], off[2];
  int tid = threadIdx.x;
  int base = tid * 64;
  int s = 0;
  #pragma unroll 8
  for (int i = 0; i < 64; ++i) s += histHi[base + i];
  int total;
  int incl = block_scan_i(s, ws, &total);
  int lo = incl - s;
  if (r0 >= lo && r0 < incl) { chunk[0] = tid; off[0] = r0 - lo; }
  if (r1 >= lo && r1 < incl) { chunk[1] = tid; off[1] = r1 - lo; }
  __syncthreads();
  int w = tid >> 6, lane = tid & 63;
  if (w < 2) {
    int ch = chunk[w], ofs = off[w];
    int c = histHi[ch * 64 + lane];
    int inc = wave_incl_scan(c);
    if (ofs >= inc - c && ofs < inc) {
      if (w == 0) { sc->binA = ch * 64 + lane; sc->rA = ofs - (inc - c); }
      else        { sc->binB = ch * 64 + lane; sc->rB = ofs - (inc - c); }
    }
  }
}

// ---------------- K7b: low-16-bit histograms within selected bins ----------------
__global__ void k_hist2(const float* mag, const Scalars* sc, int* histA, int* histB, int n) {
  int i = blockIdx.x * blockDim.x + threadIdx.x;
  if (i >= n) return;
  unsigned bits = __float_as_uint(mag[i]);
  int h = (int)(bits >> 16);
  int lo = (int)(bits & 0xFFFFu);
  if (h == sc->binA) atomicAdd(&histA[lo], 1);
  if (h == sc->binB) atomicAdd(&histB[lo], 1);
}

// ---------------- K7c: resolve order statistics + lerp (numpy branch) ------------
__global__ void __launch_bounds__(1024) k_thresh(const int* histA, const int* histB,
                                                 Scalars* sc, double tfrac) {
  __shared__ int ws[16];
  __shared__ int chunkS, offS;
  __shared__ int lowA, lowB;
  int tid = threadIdx.x, lane = tid & 63;
  int rA = sc->rA, rB = sc->rB;
  int binA = sc->binA, binB = sc->binB;

  {
    int s = 0, base = tid * 64;
    #pragma unroll 8
    for (int i = 0; i < 64; ++i) s += histA[base + i];
    int total;
    int incl = block_scan_i(s, ws, &total);
    int lo = incl - s;
    if (rA >= lo && rA < incl) { chunkS = tid; offS = rA - lo; }
    __syncthreads();
    if (tid < 64) {
      int c = histA[chunkS * 64 + lane];
      int inc = wave_incl_scan(c);
      if (offS >= inc - c && offS < inc) lowA = chunkS * 64 + lane;
    }
    __syncthreads();
  }
  {
    int s = 0, base = tid * 64;
    #pragma unroll 8
    for (int i = 0; i < 64; ++i) s += histB[base + i];
    int total;
    int incl = block_scan_i(s, ws, &total);
    int lo = incl - s;
    if (rB >= lo && rB < incl) { chunkS = tid; offS = rB - lo; }
    __syncthreads();
    if (tid < 64) {
      int c = histB[chunkS * 64 + lane];
      int inc = wave_incl_scan(c);
      if (offS >= inc - c && offS < inc) lowB = chunkS * 64 + lane;
    }
    __syncthreads();
  }
  if (tid == 0) {
    unsigned bitsLo = ((unsigned)binA << 16) | (unsigned)lowA;
    unsigned bitsHi = ((unsigned)binB << 16) | (unsigned)lowB;
    double a = (double)__uint_as_float(bitsLo);
    double b = (double)__uint_as_float(bitsHi);
    double t = tfrac;
    double th = (t >= 0.5) ? (b - (b - a) * (1.0 - t)) : (a + (b - a) * t);
    sc->thresh = (float)th;
  }
}

// ---------------- K8: masked huber + cosine reductions ---------------------------
__global__ void k_loss(const float* __restrict__ pred, const float* __restrict__ grid,
                       const float* __restrict__ tgt, const float* __restrict__ mag,
                       Scalars* sc, int n) {
  __shared__ double shH[256];
  __shared__ double shC[256];
  __shared__ int shN[256];
  __shared__ int shM[256];
  int tid = threadIdx.x;
  int i = blockIdx.x * blockDim.x + tid;
  double hub = 0.0, cs = 0.0;
  int c1 = 0, cmd = 0;
  if (i < n) {
    float th = sc->thresh;
    float m = mag[i];
    if (m <= th) {
      c1 = 1;
      float tox = __fsub_rn(tgt[3*i],   grid[3*i]);
      float toy = __fsub_rn(tgt[3*i+1], grid[3*i+1]);
      float toz = __fsub_rn(tgt[3*i+2], grid[3*i+2]);
      float px = pred[3*i], py = pred[3*i+1], pz = pred[3*i+2];
      float d0 = __fsub_rn(px, tox), d1 = __fsub_rn(py, toy), d2 = __fsub_rn(pz, toz);
      float a0 = fabsf(d0), a1 = fabsf(d1), a2 = fabsf(d2);
      float h0 = (a0 < 1.f) ? __fmul_rn(__fmul_rn(0.5f, d0), d0) : __fsub_rn(a0, 0.5f);
      float h1 = (a1 < 1.f) ? __fmul_rn(__fmul_rn(0.5f, d1), d1) : __fsub_rn(a1, 0.5f);
      float h2 = (a2 < 1.f) ? __fmul_rn(__fmul_rn(0.5f, d2), d2) : __fsub_rn(a2, 0.5f);
      hub = (double)h0 + (double)h1 + (double)h2;
      if (m > 0.f) {
        cmd = 1;
        float ps = __fadd_rn(__fadd_rn(__fmul_rn(px,px), __fmul_rn(py,py)), __fmul_rn(pz,pz));
        float pn = (ps > 0.f) ? sqrtf(ps) : 0.f;
        float dotp = __fadd_rn(__fadd_rn(__fmul_rn(px,tox), __fmul_rn(py,toy)),
                               __fmul_rn(pz,toz));
        float den = fmaxf(__fmul_rn(pn, m), 1e-4f);
        cs = (double)__fdiv_rn(dotp, den);
      }
    }
  }
  shH[tid] = hub; shC[tid] = cs; shN[tid] = c1; shM[tid] = cmd;
  __syncthreads();
  for (int off = 128; off > 0; off >>= 1) {
    if (tid < off) {
      shH[tid] += shH[tid+off];
      shC[tid] += shC[tid+off];
      shN[tid] += shN[tid+off];
      shM[tid] += shM[tid+off];
    }
    __syncthreads();
  }
  if (tid == 0) {
    atomicAdd(&sc->hub, shH[0]);
    atomicAdd(&sc->cosSum, shC[0]);
    atomicAdd(&sc->n1, shN[0]);
    atomicAdd(&sc->nmd, shM[0]);
  }
}

// ---------------- K9: finalize ---------------------------------------------------
__global__ void k_final(const Scalars* sc, float* out) {
  double n1 = (double)sc->n1;
  double l1 = (sc->n1 > 0) ? (sc->hub / fmax(n1 * 3.0, 1.0)) : 0.0;
  double nmd = (double)sc->nmd;
  double ld = (sc->nmd > 0) ? (1.0 - sc->cosSum / fmax(nmd, 1.0)) : 0.0;
  out[0] = (float)l1;
  out[1] = (float)ld;
}

extern "C" void kernel_launch(void* const* d_in, const int* in_sizes, int n_in,
                              void* d_out, int out_size, void* d_ws, size_t ws_size,
                              hipStream_t stream) {
  const float* pred  = (const float*)d_in[0];
  const float* grid  = (const float*)d_in[1];
  const int*   label = (const int*)d_in[2];
  const int*   batch = (const int*)d_in[3];
  int n = in_sizes[2];

  char* p = (char*)d_ws;
  auto take = [&](size_t bytes) -> char* {
    char* r = p;
    p += (bytes + 255) & ~(size_t)255;
    return r;
  };
  int*    cnt      = (int*)   take((size_t)SLOTS*4);
  float*  sx       = (float*) take((size_t)SLOTS*4);
  float*  sy       = (float*) take((size_t)SLOTS*4);
  float*  sz       = (float*) take((size_t)SLOTS*4);
  int*    lmask    = (int*)   take((size_t)SLOTS*4);
  float4* ctr      = (float4*)take((size_t)SLOTS*16);
  float4* pC       = (float4*)take((size_t)SLOTS*16);
  int*    blockCnt = (int*)   take((size_t)NBLK*NCODE*4);
  int*    blockBase= (int*)   take((size_t)NBLK*NCODE*4);
  int*    codeBase = (int*)   take(NCODE*4);
  int*    codeCnt  = (int*)   take(NCODE*4);
  int*    blCnt    = (int*)   take(16*4);
  float*  blSum    = (float*) take(48*4);
  int*    hists    = (int*)   take((size_t)3*65536*4);
  float*  tgt      = (float*) take((size_t)n*3*4);
  float*  mag      = (float*) take((size_t)n*4);
  int*    missIdx  = (int*)   take((size_t)n*4);
  Scalars* sc      = (Scalars*)take(sizeof(Scalars));

  int* histHi = hists;
  int* histA  = hists + 65536;
  int* histB  = hists + 131072;

  int nb = (n + 255) / 256;

  k_init<<<768, 256, 0, stream>>>(cnt, sx, sy, sz, lmask, blCnt, blSum, hists, sc);
  k_scatter<<<nb, 256, 0, stream>>>(grid, label, batch, cnt, sx, sy, sz, lmask,
                                    blCnt, blSum, n);
  k_prep<<<NBLK, 256, 0, stream>>>(cnt, sx, sy, sz, lmask, ctr, blockCnt);
  k_bases<<<1, 64, 0, stream>>>(blockCnt, blockBase, codeBase, codeCnt, sc);
  k_compact<<<NBLK, 256, 0, stream>>>(ctr, blockBase, codeBase, pC);
  k_targets<<<nb, 256, 0, stream>>>(grid, label, batch, ctr, blCnt, blSum,
                                    tgt, mag, missIdx, sc, n);
  k_fallback<<<1024, 256, 0, stream>>>(grid, label, batch, pC, codeBase, codeCnt,
                                       missIdx, sc, tgt, mag);
  k_hista<<<nb, 256, 0, stream>>>(mag, histHi, n);

  double vi = 0.99 * (double)(n - 1);
  int r0 = (int)vi;
  int r1 = r0 + 1; if (r1 > n - 1) r1 = n - 1;
  double tfrac = vi - (double)r0;

  k_selbins<<<1, 1024, 0, stream>>>(histHi, sc, r0, r1);
  k_hist2<<<nb, 256, 0, stream>>>(mag, sc, histA, histB, n);
  k_thresh<<<1, 1024, 0, stream>>>(histA, histB, sc, tfrac);
  k_loss<<<nb, 256, 0, stream>>>(pred, grid, tgt, mag, sc, n);
  k_final<<<1, 1, 0, stream>>>(sc, (float*)d_out);
}

// Round 7
// 215.296 us; speedup vs baseline: 11.2995x; 1.3072x over previous
//
#include <hip/hip_runtime.h>
#include <climits>

#define VOXD 25
#define SLOT3 (VOXD*VOXD*VOXD)      // 15625
#define SLOTS (2*SLOT3)             // 31250
#define NCLS 8
#define NCODE 16
#define NBLK ((SLOTS + 255) / 256)  // 123
#define HB 2048                     // radix bins (11 bits)

struct Scalars {
  double hub;
  double cosSum;
  int n1;
  int nmd;
  int missCount;
  int nPure;
  int binA, rA, binB, rB;
  float thresh;
  int pad;
};

__device__ __forceinline__ int voxslot(int b, int vx, int vy, int vz) {
  return ((b * VOXD + vx) * VOXD + vy) * VOXD + vz;
}

// ---- block-wide inclusive scan (int), 1024 threads = 16 waves ----
__device__ __forceinline__ int block_scan_i(int v, int* ws, int* total) {
  int lane = threadIdx.x & 63, w = threadIdx.x >> 6;
  int s = v;
  #pragma unroll
  for (int off = 1; off < 64; off <<= 1) {
    int t = __shfl_up(s, off, 64);
    if (lane >= off) s += t;
  }
  if (lane == 63) ws[w] = s;
  __syncthreads();
  if (threadIdx.x < 16) {
    int x = ws[threadIdx.x];
    #pragma unroll
    for (int off = 1; off < 16; off <<= 1) {
      int t = __shfl_up(x, off, 64);
      if (lane >= off) x += t;
    }
    ws[threadIdx.x] = x;
  }
  __syncthreads();
  if (w > 0) s += ws[w - 1];
  *total = ws[15];
  __syncthreads();
  return s;
}

// ---- 256-thread packed u64 scan (16 codes x 16-bit fields), 4 waves ----
__device__ __forceinline__ void scan4_256(unsigned long long v[4],
                                          unsigned long long* ws /*16*/) {
  int lane = threadIdx.x & 63, w = threadIdx.x >> 6;
  #pragma unroll
  for (int q = 0; q < 4; ++q) {
    unsigned long long s = v[q];
    #pragma unroll
    for (int off = 1; off < 64; off <<= 1) {
      unsigned long long t = __shfl_up(s, off, 64);
      if (lane >= off) s += t;
    }
    v[q] = s;
    if (lane == 63) ws[q * 4 + w] = s;
  }
  __syncthreads();
  if (threadIdx.x < 16) {
    int q = threadIdx.x >> 2, idx = threadIdx.x & 3;
    unsigned long long x = ws[q * 4 + idx];
    #pragma unroll
    for (int off = 1; off < 4; off <<= 1) {
      unsigned long long t = __shfl_up(x, off, 64);
      if (idx >= off) x += t;
    }
    ws[q * 4 + idx] = x;
  }
  __syncthreads();
  #pragma unroll
  for (int q = 0; q < 4; ++q) if (w > 0) v[q] += ws[q * 4 + w - 1];
}

// ---------------- K1: zero-init ----------------
__global__ void k_init(int* cnt, float* sx, float* sy, float* sz, int* lmask,
                       int* blCnt, float* blSum, int* cntAB, Scalars* sc) {
  int i = blockIdx.x * blockDim.x + threadIdx.x;
  if (i < SLOTS) {
    cnt[i] = 0; sx[i] = 0.f; sy[i] = 0.f; sz[i] = 0.f; lmask[i] = 0;
  }
  if (i < 16) { blCnt[i] = 0; blSum[3*i] = 0.f; blSum[3*i+1] = 0.f; blSum[3*i+2] = 0.f; }
  if (i < 2) cntAB[i] = 0;
  if (i == 0) {
    sc->hub = 0.0; sc->cosSum = 0.0; sc->n1 = 0; sc->nmd = 0;
    sc->missCount = 0; sc->nPure = 0;
  }
}

// ---------------- K2: per-point scatter; label bitmask; LDS-agg (b,l) stats ------
__global__ void k_scatter(const float* __restrict__ grid, const int* __restrict__ label,
                          const int* __restrict__ batch,
                          int* cnt, float* sx, float* sy, float* sz, int* lmask,
                          int* blCnt, float* blSum, int n) {
  __shared__ int sCnt[NCODE];
  __shared__ float sSum[3 * NCODE];
  int tid = threadIdx.x;
  if (tid < NCODE) sCnt[tid] = 0;
  if (tid < 3 * NCODE) sSum[tid] = 0.f;
  __syncthreads();
  int i = blockIdx.x * blockDim.x + tid;
  if (i < n) {
    float gx = grid[3*i], gy = grid[3*i+1], gz = grid[3*i+2];
    int vx = (int)floorf(gx * (1.0f/16.0f));
    int vy = (int)floorf(gy * (1.0f/16.0f));
    int vz = (int)floorf(gz * (1.0f/16.0f));
    int b = batch[i], l = label[i];
    int s = voxslot(b, vx, vy, vz);
    atomicAdd(&cnt[s], 1);
    atomicAdd(&sx[s], gx); atomicAdd(&sy[s], gy); atomicAdd(&sz[s], gz);
    atomicOr(&lmask[s], 1 << l);
    int bl = b * NCLS + l;
    atomicAdd(&sCnt[bl], 1);
    atomicAdd(&sSum[3*bl], gx); atomicAdd(&sSum[3*bl+1], gy); atomicAdd(&sSum[3*bl+2], gz);
  }
  __syncthreads();
  if (tid < NCODE && sCnt[tid] != 0) atomicAdd(&blCnt[tid], sCnt[tid]);
  if (tid < 3 * NCODE && sSum[tid] != 0.f) atomicAdd(&blSum[tid], sSum[tid]);
}

// ---------------- K3a: consolidate slot table to float4 + per-block code counts --
__global__ void k_prep(const int* cnt, const float* sx, const float* sy, const float* sz,
                       const int* lmask, float4* ctr, int* blockCnt) {
  __shared__ int sc16[NCODE];
  if (threadIdx.x < NCODE) sc16[threadIdx.x] = 0;
  __syncthreads();
  int s = blockIdx.x * 256 + threadIdx.x;
  if (s < SLOTS) {
    int c = cnt[s];
    float4 v = make_float4(0.f, 0.f, 0.f, __int_as_float(-2));
    if (c > 0) {
      float fc = (float)c;
      float cx = __fdiv_rn(sx[s], fc);
      float cy = __fdiv_rn(sy[s], fc);
      float cz = __fdiv_rn(sz[s], fc);
      int m = lmask[s];
      bool pure = (m & (m - 1)) == 0;
      int lbl = __ffs(m) - 1;
      int meta = pure ? lbl : -1;
      v = make_float4(cx, cy, cz, __int_as_float(meta));
      if (pure) atomicAdd(&sc16[(s / SLOT3) * NCLS + lbl], 1);
    }
    ctr[s] = v;
  }
  __syncthreads();
  if (threadIdx.x < NCODE) blockCnt[blockIdx.x * NCODE + threadIdx.x] = sc16[threadIdx.x];
}

// ---------------- K3b: bases per (block,code) and per code -----------------------
__global__ void k_bases(const int* blockCnt, int* blockBase, int* codeBase,
                        int* codeCnt, Scalars* sc) {
  __shared__ int tot[NCODE];
  int c = threadIdx.x;
  if (c < NCODE) {
    int run = 0;
    for (int b = 0; b < NBLK; ++b) {
      blockBase[b * NCODE + c] = run;
      run += blockCnt[b * NCODE + c];
    }
    tot[c] = run;
  }
  __syncthreads();
  if (c == 0) {
    int cum = 0;
    for (int k = 0; k < NCODE; ++k) { codeBase[k] = cum; codeCnt[k] = tot[k]; cum += tot[k]; }
    sc->nPure = cum;
  }
}

// ---------------- K4: compact pure clusters into per-code buckets (float4) -------
__global__ void k_compact(const float4* __restrict__ ctr,
                          const int* blockBase, const int* codeBase, float4* pC) {
  __shared__ unsigned long long ws[16];
  int s = blockIdx.x * 256 + threadIdx.x;
  int f = 0, code = 0;
  float4 cv = make_float4(0.f, 0.f, 0.f, 0.f);
  if (s < SLOTS) {
    cv = ctr[s];
    int meta = __float_as_int(cv.w);
    if (meta >= 0) { f = 1; code = (s / SLOT3) * NCLS + meta; }
  }
  unsigned long long v[4] = {0ULL, 0ULL, 0ULL, 0ULL};
  if (f) v[code >> 2] = 1ULL << (16 * (code & 3));
  scan4_256(v, ws);
  if (f) {
    int rank = (int)((v[code >> 2] >> (16 * (code & 3))) & 0xFFFFULL) - 1;
    int pos = codeBase[code] + blockBase[blockIdx.x * NCODE + code] + rank;
    float c2 = __fadd_rn(__fadd_rn(__fmul_rn(cv.x,cv.x), __fmul_rn(cv.y,cv.y)),
                         __fmul_rn(cv.z,cv.z));
    pC[pos] = make_float4(cv.x, cv.y, cv.z, c2);
  }
}

// ---------------- K5: probe targets, block-aggregated miss list ------------------
__global__ void k_targets(const float* __restrict__ grid, const int* __restrict__ label,
                          const int* __restrict__ batch,
                          const float4* __restrict__ ctr,
                          const int* __restrict__ blCnt, const float* __restrict__ blSum,
                          float* tgt, float* mag,
                          int* missIdx, Scalars* sc, int n) {
  __shared__ int wcnt[4];
  __shared__ int sbase;
  int tid = threadIdx.x, lane = tid & 63, w = tid >> 6;
  int i = blockIdx.x * blockDim.x + tid;
  bool active = (i < n);
  bool miss = false;

  if (active) {
    float gx = grid[3*i], gy = grid[3*i+1], gz = grid[3*i+2];
    int vx = (int)floorf(gx * (1.0f/16.0f));
    int vy = (int)floorf(gy * (1.0f/16.0f));
    int vz = (int)floorf(gz * (1.0f/16.0f));
    int b = batch[i], l = label[i];
    int s = voxslot(b, vx, vy, vz);

    float4 own = ctr[s];
    bool purept = (__float_as_int(own.w) >= 0);

    int bl = b * NCLS + l;
    float fbc = (float)max(blCnt[bl], 1);
    float gcx = __fdiv_rn(blSum[3*bl],   fbc);
    float gcy = __fdiv_rn(blSum[3*bl+1], fbc);
    float gcz = __fdiv_rn(blSum[3*bl+2], fbc);

    float dx = __fsub_rn(gcx, own.x);
    float dy = __fsub_rn(gcy, own.y);
    float dz = __fsub_rn(gcz, own.z);
    int sgx = (dx > 0.f) ? 1 : ((dx < 0.f) ? -1 : 0);
    int sgy = (dy > 0.f) ? 1 : ((dy < 0.f) ? -1 : 0);
    int sgz = (dz > 0.f) ? 1 : ((dz < 0.f) ? -1 : 0);

    int ax1 = vx + sgx,     ay1 = vy + sgy,     az1 = vz + sgz;
    int ax2 = vx + 2 * sgx, ay2 = vy + 2 * sgy, az2 = vz + 2 * sgz;
    bool v1 = (unsigned)ax1 < (unsigned)VOXD && (unsigned)ay1 < (unsigned)VOXD &&
              (unsigned)az1 < (unsigned)VOXD;
    bool v2 = (unsigned)ax2 < (unsigned)VOXD && (unsigned)ay2 < (unsigned)VOXD &&
              (unsigned)az2 < (unsigned)VOXD;

    float4 q1 = make_float4(0.f, 0.f, 0.f, __int_as_float(-3));
    float4 q2 = q1;
    if (v1) q1 = ctr[voxslot(b, ax1, ay1, az1)];
    if (v2) q2 = ctr[voxslot(b, ax2, ay2, az2)];

    bool hit1 = v1 && (__float_as_int(q1.w) == l);
    bool hit2 = v2 && (__float_as_int(q2.w) == l);
    bool hit = hit1 || hit2;

    float tx = hit1 ? q1.x : (hit2 ? q2.x : gx);
    float ty = hit1 ? q1.y : (hit2 ? q2.y : gy);
    float tz = hit1 ? q1.z : (hit2 ? q2.z : gz);

    tgt[3*i] = tx; tgt[3*i+1] = ty; tgt[3*i+2] = tz;
    miss = (!purept && !hit);
    if (!miss) {
      float tox = __fsub_rn(tx, gx), toy = __fsub_rn(ty, gy), toz = __fsub_rn(tz, gz);
      float ssq = __fadd_rn(__fadd_rn(__fmul_rn(tox,tox), __fmul_rn(toy,toy)),
                            __fmul_rn(toz,toz));
      float m = (ssq > 0.f) ? sqrtf(ssq) : 0.f;
      mag[i] = m;
    }
  }
  unsigned long long mb = __ballot(miss);
  int mc = __popcll(mb);
  if (lane == 0) wcnt[w] = mc;
  __syncthreads();
  if (tid == 0) {
    int tot = wcnt[0] + wcnt[1] + wcnt[2] + wcnt[3];
    sbase = (tot > 0) ? atomicAdd(&sc->missCount, tot) : 0;
  }
  __syncthreads();
  if (miss) {
    int base = sbase;
    for (int q = 0; q < 4; ++q) if (q < w) base += wcnt[q];
    int pos = base + __popcll(mb & ((1ULL << lane) - 1ULL));
    missIdx[pos] = i;
  }
}

// ---------------- K6: fallback — one wave per miss point; writes mag only --------
__global__ void k_fallback(const float* __restrict__ grid, const int* __restrict__ label,
                           const int* __restrict__ batch,
                           const float4* __restrict__ pC,
                           const int* __restrict__ codeBase, const int* __restrict__ codeCnt,
                           const int* __restrict__ missIdx, const Scalars* sc,
                           float* tgt, float* mag) {
  int lane = threadIdx.x & 63;
  int wid = (blockIdx.x * blockDim.x + threadIdx.x) >> 6;
  int nWaves = (gridDim.x * blockDim.x) >> 6;
  int nMiss = sc->missCount;

  for (int t = wid; t < nMiss; t += nWaves) {
    int idx = missIdx[t];
    float gx = grid[3*idx], gy = grid[3*idx+1], gz = grid[3*idx+2];
    float p2 = __fadd_rn(__fadd_rn(__fmul_rn(gx,gx), __fmul_rn(gy,gy)), __fmul_rn(gz,gz));
    int code = batch[idx] * NCLS + label[idx];
    int j0 = codeBase[code];
    int cc = codeCnt[code];

    float bestD = 1e38f;
    int bestJ = -1;
    for (int j = lane; j < cc; j += 64) {
      float4 c = pC[j0 + j];
      float dot = __fadd_rn(__fadd_rn(__fmul_rn(gx,c.x), __fmul_rn(gy,c.y)),
                            __fmul_rn(gz,c.z));
      float d2 = __fadd_rn(__fsub_rn(p2, __fmul_rn(2.0f, dot)), c.w);
      if (d2 < bestD) { bestD = d2; bestJ = j; }
    }
    unsigned fb = __float_as_uint(bestD);
    fb = (fb >> 31) ? ~fb : (fb | 0x80000000u);
    unsigned long long key = ((unsigned long long)fb << 32) | (unsigned)bestJ;
    #pragma unroll
    for (int off = 1; off < 64; off <<= 1) {
      unsigned long long o = __shfl_xor(key, off, 64);
      key = (o < key) ? o : key;
    }
    if (lane == 0) {
      if (cc > 0) {
        int j = (int)(unsigned)(key & 0xFFFFFFFFULL);
        float4 c = pC[j0 + j];
        tgt[3*idx] = c.x; tgt[3*idx+1] = c.y; tgt[3*idx+2] = c.z;
        float tox = __fsub_rn(c.x, gx), toy = __fsub_rn(c.y, gy), toz = __fsub_rn(c.z, gz);
        float ssq = __fadd_rn(__fadd_rn(__fmul_rn(tox,tox), __fmul_rn(toy,toy)),
                              __fmul_rn(toz,toz));
        mag[idx] = (ssq > 0.f) ? sqrtf(ssq) : 0.f;
      } else {
        mag[idx] = 0.f;
      }
    }
  }
}

// ---------------- K7a: LDS-private coarse histogram (bits >> 21), no atomics -----
__global__ void __launch_bounds__(1024) k_hist(const float* __restrict__ mag,
                                               int* ghist, int n) {
  __shared__ int h[HB];
  for (int t = threadIdx.x; t < HB; t += 1024) h[t] = 0;
  __syncthreads();
  int i = blockIdx.x * 1024 + threadIdx.x;
  if (i < n) atomicAdd(&h[__float_as_uint(mag[i]) >> 21], 1);
  __syncthreads();
  for (int t = threadIdx.x; t < HB; t += 1024)
    ghist[blockIdx.x * HB + t] = h[t];
}

// ---------------- K7b: reduce block hists + find coarse bins of r0, r1 -----------
__global__ void __launch_bounds__(1024) k_redsel(const int* __restrict__ ghist, int nhb,
                                                 Scalars* sc, int r0, int r1) {
  __shared__ int ws[16];
  __shared__ int sBinA, sRA, sBinB, sRB;
  int t = threadIdx.x;
  int s0 = 0, s1 = 0;
  for (int b = 0; b < nhb; ++b) {
    int2 v = ((const int2*)(ghist + b * HB))[t];
    s0 += v.x; s1 += v.y;
  }
  int tot;
  int incl = block_scan_i(s0 + s1, ws, &tot);
  int b1 = incl - s1, b0 = b1 - s0;
  if (r0 >= b0 && r0 < b0 + s0) { sBinA = 2*t;   sRA = r0 - b0; }
  if (r0 >= b1 && r0 < b1 + s1) { sBinA = 2*t+1; sRA = r0 - b1; }
  if (r1 >= b0 && r1 < b0 + s0) { sBinB = 2*t;   sRB = r1 - b0; }
  if (r1 >= b1 && r1 < b1 + s1) { sBinB = 2*t+1; sRB = r1 - b1; }
  __syncthreads();
  if (t == 0) { sc->binA = sBinA; sc->rA = sRA; sc->binB = sBinB; sc->rB = sRB; }
}

// ---------------- K7c: gather candidate bit-patterns for the two coarse bins -----
__global__ void k_gather(const float* __restrict__ mag, const Scalars* sc,
                         unsigned* bufA, unsigned* bufB, int* cntAB, int n) {
  int i = blockIdx.x * blockDim.x + threadIdx.x;
  int lane = threadIdx.x & 63;
  unsigned bits = 0;
  bool inA = false, inB = false;
  if (i < n) {
    bits = __float_as_uint(mag[i]);
    unsigned c = bits >> 21;
    inA = (c == (unsigned)sc->binA);
    inB = (c == (unsigned)sc->binB);
  }
  {
    unsigned long long mb = __ballot(inA);
    int mc = __popcll(mb);
    int base = 0;
    if (lane == 0 && mc > 0) base = atomicAdd(&cntAB[0], mc);
    base = __shfl(base, 0, 64);
    if (inA) bufA[base + __popcll(mb & ((1ULL << lane) - 1ULL))] = bits;
  }
  {
    unsigned long long mb = __ballot(inB);
    int mc = __popcll(mb);
    int base = 0;
    if (lane == 0 && mc > 0) base = atomicAdd(&cntAB[1], mc);
    base = __shfl(base, 0, 64);
    if (inB) bufB[base + __popcll(mb & ((1ULL << lane) - 1ULL))] = bits;
  }
}

// ---------------- K7d helper: exact rank select within a coarse bin --------------
__device__ unsigned select_in_bin(const unsigned* __restrict__ buf, int cnt,
                                  int coarse, int rank, int* h, int* ws) {
  __shared__ int sSub, sSubR, sLow;
  // level 1: bits[20:10], 2048 bins
  for (int t = threadIdx.x; t < HB; t += 1024) h[t] = 0;
  __syncthreads();
  for (int t = threadIdx.x; t < cnt; t += 1024)
    atomicAdd(&h[(buf[t] >> 10) & 0x7FF], 1);
  __syncthreads();
  int t = threadIdx.x;
  int s0 = h[2*t], s1 = h[2*t+1];
  int tot;
  int incl = block_scan_i(s0 + s1, ws, &tot);
  int b1 = incl - s1, b0 = b1 - s0;
  if (rank >= b0 && rank < b0 + s0) { sSub = 2*t;   sSubR = rank - b0; }
  if (rank >= b1 && rank < b1 + s1) { sSub = 2*t+1; sSubR = rank - b1; }
  __syncthreads();
  int subv = sSub, subr = sSubR;
  // level 2: bits[9:0], 1024 bins
  h[t] = 0;
  __syncthreads();
  for (int q = threadIdx.x; q < cnt; q += 1024) {
    unsigned v = buf[q];
    if ((int)((v >> 10) & 0x7FF) == subv) atomicAdd(&h[v & 0x3FF], 1);
  }
  __syncthreads();
  int c = h[t];
  int tot2;
  int incl2 = block_scan_i(c, ws, &tot2);
  int lb = incl2 - c;
  if (subr >= lb && subr < lb + c) sLow = t;
  __syncthreads();
  return ((unsigned)coarse << 21) | ((unsigned)subv << 10) | (unsigned)sLow;
}

// ---------------- K7d: exact order statistics + lerp (numpy branch) --------------
__global__ void __launch_bounds__(1024) k_sel(const unsigned* __restrict__ bufA,
                                              const unsigned* __restrict__ bufB,
                                              const int* __restrict__ cntAB,
                                              Scalars* sc, double tfrac) {
  __shared__ int h[HB];
  __shared__ int ws[16];
  unsigned va = select_in_bin(bufA, cntAB[0], sc->binA, sc->rA, h, ws);
  __syncthreads();
  unsigned vb = select_in_bin(bufB, cntAB[1], sc->binB, sc->rB, h, ws);
  if (threadIdx.x == 0) {
    double a = (double)__uint_as_float(va);
    double b = (double)__uint_as_float(vb);
    double th = (tfrac >= 0.5) ? (b - (b - a) * (1.0 - tfrac)) : (a + (b - a) * tfrac);
    sc->thresh = (float)th;
  }
}

// ---------------- K8: masked huber + cosine reductions ---------------------------
__global__ void k_loss(const float* __restrict__ pred, const float* __restrict__ grid,
                       const float* __restrict__ tgt, const float* __restrict__ mag,
                       Scalars* sc, int n) {
  __shared__ double shH[256];
  __shared__ double shC[256];
  __shared__ int shN[256];
  __shared__ int shM[256];
  int tid = threadIdx.x;
  int i = blockIdx.x * blockDim.x + tid;
  double hub = 0.0, cs = 0.0;
  int c1 = 0, cmd = 0;
  if (i < n) {
    float th = sc->thresh;
    float m = mag[i];
    if (m <= th) {
      c1 = 1;
      float tox = __fsub_rn(tgt[3*i],   grid[3*i]);
      float toy = __fsub_rn(tgt[3*i+1], grid[3*i+1]);
      float toz = __fsub_rn(tgt[3*i+2], grid[3*i+2]);
      float px = pred[3*i], py = pred[3*i+1], pz = pred[3*i+2];
      float d0 = __fsub_rn(px, tox), d1 = __fsub_rn(py, toy), d2 = __fsub_rn(pz, toz);
      float a0 = fabsf(d0), a1 = fabsf(d1), a2 = fabsf(d2);
      float h0 = (a0 < 1.f) ? __fmul_rn(__fmul_rn(0.5f, d0), d0) : __fsub_rn(a0, 0.5f);
      float h1 = (a1 < 1.f) ? __fmul_rn(__fmul_rn(0.5f, d1), d1) : __fsub_rn(a1, 0.5f);
      float h2 = (a2 < 1.f) ? __fmul_rn(__fmul_rn(0.5f, d2), d2) : __fsub_rn(a2, 0.5f);
      hub = (double)h0 + (double)h1 + (double)h2;
      if (m > 0.f) {
        cmd = 1;
        float ps = __fadd_rn(__fadd_rn(__fmul_rn(px,px), __fmul_rn(py,py)), __fmul_rn(pz,pz));
        float pn = (ps > 0.f) ? sqrtf(ps) : 0.f;
        float dotp = __fadd_rn(__fadd_rn(__fmul_rn(px,tox), __fmul_rn(py,toy)),
                               __fmul_rn(pz,toz));
        float den = fmaxf(__fmul_rn(pn, m), 1e-4f);
        cs = (double)__fdiv_rn(dotp, den);
      }
    }
  }
  shH[tid] = hub; shC[tid] = cs; shN[tid] = c1; shM[tid] = cmd;
  __syncthreads();
  for (int off = 128; off > 0; off >>= 1) {
    if (tid < off) {
      shH[tid] += shH[tid+off];
      shC[tid] += shC[tid+off];
      shN[tid] += shN[tid+off];
      shM[tid] += shM[tid+off];
    }
    __syncthreads();
  }
  if (tid == 0) {
    atomicAdd(&sc->hub, shH[0]);
    atomicAdd(&sc->cosSum, shC[0]);
    atomicAdd(&sc->n1, shN[0]);
    atomicAdd(&sc->nmd, shM[0]);
  }
}

// ---------------- K9: finalize ---------------------------------------------------
__global__ void k_final(const Scalars* sc, float* out) {
  double n1 = (double)sc->n1;
  double l1 = (sc->n1 > 0) ? (sc->hub / fmax(n1 * 3.0, 1.0)) : 0.0;
  double nmd = (double)sc->nmd;
  double ld = (sc->nmd > 0) ? (1.0 - sc->cosSum / fmax(nmd, 1.0)) : 0.0;
  out[0] = (float)l1;
  out[1] = (float)ld;
}

extern "C" void kernel_launch(void* const* d_in, const int* in_sizes, int n_in,
                              void* d_out, int out_size, void* d_ws, size_t ws_size,
                              hipStream_t stream) {
  const float* pred  = (const float*)d_in[0];
  const float* grid  = (const float*)d_in[1];
  const int*   label = (const int*)d_in[2];
  const int*   batch = (const int*)d_in[3];
  int n = in_sizes[2];
  int nhb = (n + 1023) / 1024;

  char* p = (char*)d_ws;
  auto take = [&](size_t bytes) -> char* {
    char* r = p;
    p += (bytes + 255) & ~(size_t)255;
    return r;
  };
  int*    cnt      = (int*)   take((size_t)SLOTS*4);
  float*  sx       = (float*) take((size_t)SLOTS*4);
  float*  sy       = (float*) take((size_t)SLOTS*4);
  float*  sz       = (float*) take((size_t)SLOTS*4);
  int*    lmask    = (int*)   take((size_t)SLOTS*4);
  float4* ctr      = (float4*)take((size_t)SLOTS*16);
  float4* pC       = (float4*)take((size_t)SLOTS*16);
  int*    blockCnt = (int*)   take((size_t)NBLK*NCODE*4);
  int*    blockBase= (int*)   take((size_t)NBLK*NCODE*4);
  int*    codeBase = (int*)   take(NCODE*4);
  int*    codeCnt  = (int*)   take(NCODE*4);
  int*    blCnt    = (int*)   take(16*4);
  float*  blSum    = (float*) take(48*4);
  int*    ghist    = (int*)   take((size_t)nhb*HB*4);
  unsigned* bufA   = (unsigned*)take((size_t)n*4);
  unsigned* bufB   = (unsigned*)take((size_t)n*4);
  int*    cntAB    = (int*)   take(2*4);
  float*  tgt      = (float*) take((size_t)n*3*4);
  float*  mag      = (float*) take((size_t)n*4);
  int*    missIdx  = (int*)   take((size_t)n*4);
  Scalars* sc      = (Scalars*)take(sizeof(Scalars));

  int nb = (n + 255) / 256;

  k_init<<<NBLK, 256, 0, stream>>>(cnt, sx, sy, sz, lmask, blCnt, blSum, cntAB, sc);
  k_scatter<<<nb, 256, 0, stream>>>(grid, label, batch, cnt, sx, sy, sz, lmask,
                                    blCnt, blSum, n);
  k_prep<<<NBLK, 256, 0, stream>>>(cnt, sx, sy, sz, lmask, ctr, blockCnt);
  k_bases<<<1, 64, 0, stream>>>(blockCnt, blockBase, codeBase, codeCnt, sc);
  k_compact<<<NBLK, 256, 0, stream>>>(ctr, blockBase, codeBase, pC);
  k_targets<<<nb, 256, 0, stream>>>(grid, label, batch, ctr, blCnt, blSum,
                                    tgt, mag, missIdx, sc, n);
  k_fallback<<<1024, 256, 0, stream>>>(grid, label, batch, pC, codeBase, codeCnt,
                                       missIdx, sc, tgt, mag);
  k_hist<<<nhb, 1024, 0, stream>>>(mag, ghist, n);

  double vi = 0.99 * (double)(n - 1);
  int r0 = (int)vi;
  int r1 = r0 + 1; if (r1 > n - 1) r1 = n - 1;
  double tfrac = vi - (double)r0;

  k_redsel<<<1, 1024, 0, stream>>>(ghist, nhb, sc, r0, r1);
  k_gather<<<nb, 256, 0, stream>>>(mag, sc, bufA, bufB, cntAB, n);
  k_sel<<<1, 1024, 0, stream>>>(bufA, bufB, cntAB, sc, tfrac);
  k_loss<<<nb, 256, 0, stream>>>(pred, grid, tgt, mag, sc, n);
  k_final<<<1, 1, 0, stream>>>(sc, (float*)d_out);
}